// Round 3
// baseline (1034.723 us; speedup 1.0000x reference)
//
#include <hip/hip_runtime.h>
#include <hip/hip_bf16.h>
#include <cstddef>

static constexpr int BATCH = 16;   // B
static constexpr int NPIX  = 1024; // H*W

// ---------------- input dtype detection + import to f32 ---------------------
__global__ void detect_kernel(const unsigned* __restrict__ x, int* flag) {
  __shared__ int red[256];
  const int tid = threadIdx.x;
  int cnt = 0;
  for (int i = tid; i < 4096; i += 256) {
    unsigned e = (x[i] >> 7) & 0xFFu;
    cnt += (e >= 90u && e <= 135u) ? 1 : 0;
  }
  red[tid] = cnt; __syncthreads();
  for (int s = 128; s > 0; s >>= 1) {
    if (tid < s) red[tid] += red[tid + s];
    __syncthreads();
  }
  if (tid == 0) *flag = (red[0] > 3072) ? 1 : 0;  // 1 = bf16 layout
}

struct ImportArgs {
  const void* p[46];
  int sz[46];
  int off[46];  // dst offset (floats) from workspace base
};

__global__ __launch_bounds__(256)
void import_kernel(ImportArgs a, float* __restrict__ wsf, const int* __restrict__ flag) {
  const int t = blockIdx.x;
  const int sz = a.sz[t];
  float* dst = wsf + a.off[t];
  const int isb = *flag;
  for (int i = blockIdx.y * 256 + threadIdx.x; i < sz; i += 16 * 256) {
    float v;
    if (isb) v = __uint_as_float((unsigned)((const unsigned short*)a.p[t])[i] << 16);
    else     v = ((const float*)a.p[t])[i];
    dst[i] = v;
  }
}

// ---------------- conv1x1: Y[b,o,n] = sum_c W[o,c] * X[b,c,n] (+bias) --------
template<int CIN, int OG>
__global__ __launch_bounds__(256)
void conv_kernel(const float* __restrict__ X, const float* __restrict__ W,
                 const float* __restrict__ bias, float* __restrict__ Y, int Cout) {
  __shared__ float ws[OG][CIN];
  const int tid = threadIdx.x;
  const int o0  = blockIdx.x * OG;
  const int b   = blockIdx.y;
  for (int idx = tid; idx < OG * CIN; idx += 256) {
    int k = idx / CIN, c = idx & (CIN - 1);
    ws[k][c] = W[(o0 + k) * CIN + c];
  }
  __syncthreads();
  const int n0 = tid << 2;
  float acc[OG][4];
#pragma unroll
  for (int k = 0; k < OG; ++k) { acc[k][0]=acc[k][1]=acc[k][2]=acc[k][3]=0.f; }
  const float* Xb = X + (((size_t)b * CIN) << 10) + n0;
#pragma unroll 4
  for (int c = 0; c < CIN; ++c) {
    float4 xv = *reinterpret_cast<const float4*>(Xb + ((size_t)c << 10));
#pragma unroll
    for (int k = 0; k < OG; ++k) {
      float w = ws[k][c];
      acc[k][0] = fmaf(w, xv.x, acc[k][0]);
      acc[k][1] = fmaf(w, xv.y, acc[k][1]);
      acc[k][2] = fmaf(w, xv.z, acc[k][2]);
      acc[k][3] = fmaf(w, xv.w, acc[k][3]);
    }
  }
#pragma unroll
  for (int k = 0; k < OG; ++k) {
    float bv = bias ? bias[o0 + k] : 0.f;
    float4 o;
    o.x = acc[k][0] + bv; o.y = acc[k][1] + bv;
    o.z = acc[k][2] + bv; o.w = acc[k][3] + bv;
    *reinterpret_cast<float4*>(Y + (((size_t)b * Cout + o0 + k) << 10) + n0) = o;
  }
}

// ---- fused PV: OUT[b,c,i] = sum_j exp(-E[b,i,j]) * KB[b,c,j]; also bsum ----
// E[b,i,j] = sum_c QA[b,c,i]*QB[b,c,j].  grid (16 i-tiles, B), block 256.
__global__ __launch_bounds__(256)
void fused_pv_kernel(const float* __restrict__ QA, const float* __restrict__ QB,
                     const float* __restrict__ KB, float* __restrict__ OUT,
                     float* __restrict__ bsum) {
  __shared__ float U[64][64];   // QA_i  [c][i]
  __shared__ float V[64][65];   // QB_j, then KB_j  [c][j]
  __shared__ float W[64][65];   // P = exp(-E)  [i][j]
  __shared__ float red[256];
  const int tid = threadIdx.x;
  const int b = blockIdx.y, i0 = blockIdx.x << 6;
  const int tx = tid & 15, ty = tid >> 4;
  const float* qa = QA + ((size_t)b << 16);
  const float* qb = QB + ((size_t)b << 16);
  const float* kb = KB + ((size_t)b << 16);
  for (int idx = tid; idx < 4096; idx += 256) {
    int c = idx >> 6, x = idx & 63;
    U[c][x] = qa[(c << 10) + i0 + x];
  }
  float accO[4][4] = {};
  float psum = 0.f;
  for (int j0 = 0; j0 < 1024; j0 += 64) {
    __syncthreads();  // protect V,W against previous iteration's readers
    for (int idx = tid; idx < 4096; idx += 256) {
      int c = idx >> 6, x = idx & 63;
      V[c][x] = qb[(c << 10) + j0 + x];
    }
    __syncthreads();
    float e[4][4] = {};
#pragma unroll 4
    for (int c = 0; c < 64; ++c) {
      float a[4], bb[4];
#pragma unroll
      for (int p = 0; p < 4; ++p) a[p] = U[c][(ty << 2) + p];
#pragma unroll
      for (int q = 0; q < 4; ++q) bb[q] = V[c][(tx << 2) + q];
#pragma unroll
      for (int p = 0; p < 4; ++p)
#pragma unroll
        for (int q = 0; q < 4; ++q) e[p][q] = fmaf(a[p], bb[q], e[p][q]);
    }
    __syncthreads();  // V free, W free
#pragma unroll
    for (int p = 0; p < 4; ++p)
#pragma unroll
      for (int q = 0; q < 4; ++q) {
        float pv = __expf(-e[p][q]);
        psum += pv;
        W[(ty << 2) + p][(tx << 2) + q] = pv;
      }
    for (int idx = tid; idx < 4096; idx += 256) {
      int c = idx >> 6, x = idx & 63;
      V[c][x] = kb[(c << 10) + j0 + x];
    }
    __syncthreads();
#pragma unroll 4
    for (int j = 0; j < 64; ++j) {
      float kv[4], pw[4];
#pragma unroll
      for (int k = 0; k < 4; ++k) kv[k] = V[(ty << 2) + k][j];
#pragma unroll
      for (int p = 0; p < 4; ++p) pw[p] = W[(tx << 2) + p][j];
#pragma unroll
      for (int k = 0; k < 4; ++k)
#pragma unroll
        for (int p = 0; p < 4; ++p) accO[k][p] = fmaf(kv[k], pw[p], accO[k][p]);
    }
  }
#pragma unroll
  for (int k = 0; k < 4; ++k)
#pragma unroll
    for (int p = 0; p < 4; ++p)
      OUT[((size_t)(b * 64 + (ty << 2) + k) << 10) + i0 + (tx << 2) + p] = accO[k][p];
  red[tid] = psum; __syncthreads();
  for (int s = 128; s > 0; s >>= 1) {
    if (tid < s) red[tid] += red[tid + s];
    __syncthreads();
  }
  if (tid == 0) atomicAdd(bsum + b, red[0]);
}

// ---- fused PtV: OUT[b,c,j] = sum_i exp(-E[b,i,j]) * KA[b,c,i] --------------
__global__ __launch_bounds__(256)
void fused_tpv_kernel(const float* __restrict__ QA, const float* __restrict__ QB,
                      const float* __restrict__ KA, float* __restrict__ OUT) {
  __shared__ float U[64][64];   // QB_j  [c][j]
  __shared__ float V[64][65];   // QA_i, then KA_i  [c][i]
  __shared__ float W[64][65];   // P  [i][j]
  const int tid = threadIdx.x;
  const int b = blockIdx.y, j0 = blockIdx.x << 6;
  const int tx = tid & 15, ty = tid >> 4;
  const float* qa = QA + ((size_t)b << 16);
  const float* qb = QB + ((size_t)b << 16);
  const float* ka = KA + ((size_t)b << 16);
  for (int idx = tid; idx < 4096; idx += 256) {
    int c = idx >> 6, x = idx & 63;
    U[c][x] = qb[(c << 10) + j0 + x];
  }
  float accO[4][4] = {};
  for (int i0 = 0; i0 < 1024; i0 += 64) {
    __syncthreads();
    for (int idx = tid; idx < 4096; idx += 256) {
      int c = idx >> 6, x = idx & 63;
      V[c][x] = qa[(c << 10) + i0 + x];
    }
    __syncthreads();
    float e[4][4] = {};   // i = ty4+p, j = tx4+q
#pragma unroll 4
    for (int c = 0; c < 64; ++c) {
      float a[4], bb[4];
#pragma unroll
      for (int p = 0; p < 4; ++p) a[p] = V[c][(ty << 2) + p];
#pragma unroll
      for (int q = 0; q < 4; ++q) bb[q] = U[c][(tx << 2) + q];
#pragma unroll
      for (int p = 0; p < 4; ++p)
#pragma unroll
        for (int q = 0; q < 4; ++q) e[p][q] = fmaf(a[p], bb[q], e[p][q]);
    }
    __syncthreads();
#pragma unroll
    for (int p = 0; p < 4; ++p)
#pragma unroll
      for (int q = 0; q < 4; ++q)
        W[(ty << 2) + p][(tx << 2) + q] = __expf(-e[p][q]);
    for (int idx = tid; idx < 4096; idx += 256) {
      int c = idx >> 6, x = idx & 63;
      V[c][x] = ka[(c << 10) + i0 + x];
    }
    __syncthreads();
#pragma unroll 4
    for (int i = 0; i < 64; ++i) {
      float kv[4], pw[4];
#pragma unroll
      for (int k = 0; k < 4; ++k) kv[k] = V[(ty << 2) + k][i];
#pragma unroll
      for (int p = 0; p < 4; ++p) pw[p] = W[i][(tx << 2) + p];
#pragma unroll
      for (int k = 0; k < 4; ++k)
#pragma unroll
        for (int p = 0; p < 4; ++p) accO[k][p] = fmaf(kv[k], pw[p], accO[k][p]);
    }
  }
#pragma unroll
  for (int k = 0; k < 4; ++k)
#pragma unroll
    for (int p = 0; p < 4; ++p)
      OUT[((size_t)(b * 64 + (ty << 2) + k) << 10) + j0 + (tx << 2) + p] = accO[k][p];
}

// ---------------- concat + softmax divide -----------------------------------
__global__ __launch_bounds__(256)
void concat_kernel(const float* __restrict__ xin, const float* __restrict__ att,
                   const float* __restrict__ bsum, float* __restrict__ Y) {
  int idx = blockIdx.x * 256 + threadIdx.x; // < 16*128*1024
  int n = idx & 1023, ch = (idx >> 10) & 127, b = idx >> 17;
  float v;
  if (ch < 64) v = xin[((((size_t)b << 6) + ch) << 10) + n];
  else         v = att[((((size_t)b << 6) + (ch - 64)) << 10) + n] * (1.f / bsum[b]);
  Y[idx] = v;
}

// ---------------- BN stats: per-channel scale/shift over (B, N) -------------
__global__ __launch_bounds__(256)
void bn_stats_kernel(const float* __restrict__ X, const float* __restrict__ gam,
                     const float* __restrict__ bet, float* __restrict__ scale,
                     float* __restrict__ shift, int Cch) {
  const int c = blockIdx.x, tid = threadIdx.x;
  float sum = 0.f, ss = 0.f;
  for (int t = tid; t < BATCH * NPIX; t += 256) {
    int b = t >> 10, n = t & 1023;
    float v = X[(((size_t)b * Cch + c) << 10) + n];
    sum += v; ss = fmaf(v, v, ss);
  }
  __shared__ float rs[256], rq[256];
  rs[tid] = sum; rq[tid] = ss; __syncthreads();
  for (int s = 128; s > 0; s >>= 1) {
    if (tid < s) { rs[tid] += rs[tid + s]; rq[tid] += rq[tid + s]; }
    __syncthreads();
  }
  if (tid == 0) {
    const float invN = 1.f / (BATCH * NPIX);
    float m = rs[0] * invN;
    float var = rq[0] * invN - m * m;
    float sc = gam[c] * rsqrtf(var + 1e-5f);
    scale[c] = sc;
    shift[c] = bet[c] - m * sc;
  }
}

// ---------------- elementwise BN apply + relu (in place) --------------------
__global__ __launch_bounds__(256)
void bn_relu_kernel(float* __restrict__ X, const float* __restrict__ scale,
                    const float* __restrict__ shift, int cmask) {
  const int i4 = (blockIdx.x * 256 + threadIdx.x) << 2;
  const int c = (i4 >> 10) & cmask;
  const float sc = scale[c], sh = shift[c];
  float4 v = *reinterpret_cast<const float4*>(X + i4);
  v.x = fmaxf(fmaf(v.x, sc, sh), 0.f);
  v.y = fmaxf(fmaf(v.y, sc, sh), 0.f);
  v.z = fmaxf(fmaf(v.z, sc, sh), 0.f);
  v.w = fmaxf(fmaf(v.w, sc, sh), 0.f);
  *reinterpret_cast<float4*>(X + i4) = v;
}

// ---------------- O = relu(bn(T) + R) ---------------------------------------
__global__ __launch_bounds__(256)
void epil_add_kernel(const float* __restrict__ T, const float* __restrict__ scale,
                     const float* __restrict__ shift, const float* __restrict__ R,
                     float* __restrict__ O, int cmask) {
  const int i4 = (blockIdx.x * 256 + threadIdx.x) << 2;
  const int c = (i4 >> 10) & cmask;
  const float sc = scale[c], sh = shift[c];
  float4 t = *reinterpret_cast<const float4*>(T + i4);
  float4 r = *reinterpret_cast<const float4*>(R + i4);
  float4 o;
  o.x = fmaxf(fmaf(t.x, sc, sh) + r.x, 0.f);
  o.y = fmaxf(fmaf(t.y, sc, sh) + r.y, 0.f);
  o.z = fmaxf(fmaf(t.z, sc, sh) + r.z, 0.f);
  o.w = fmaxf(fmaf(t.w, sc, sh) + r.w, 0.f);
  *reinterpret_cast<float4*>(O + i4) = o;
}

// ---------------- O = relu(bn0(T) + bn1(S)) ---------------------------------
__global__ __launch_bounds__(256)
void epil2_kernel(const float* __restrict__ T, const float* __restrict__ s0,
                  const float* __restrict__ h0, const float* __restrict__ S,
                  const float* __restrict__ s1, const float* __restrict__ h1,
                  float* __restrict__ O, int cmask) {
  const int i4 = (blockIdx.x * 256 + threadIdx.x) << 2;
  const int c = (i4 >> 10) & cmask;
  const float a0 = s0[c], b0 = h0[c], a1 = s1[c], b1 = h1[c];
  float4 t = *reinterpret_cast<const float4*>(T + i4);
  float4 s = *reinterpret_cast<const float4*>(S + i4);
  float4 o;
  o.x = fmaxf(fmaf(t.x, a0, b0) + fmaf(s.x, a1, b1), 0.f);
  o.y = fmaxf(fmaf(t.y, a0, b0) + fmaf(s.y, a1, b1), 0.f);
  o.z = fmaxf(fmaf(t.z, a0, b0) + fmaf(s.z, a1, b1), 0.f);
  o.w = fmaxf(fmaf(t.w, a0, b0) + fmaf(s.w, a1, b1), 0.f);
  *reinterpret_cast<float4*>(O + i4) = o;
}

// ---------------- final: out = bn(F) as f32 ---------------------------------
__global__ __launch_bounds__(256)
void writeout_kernel(const float* __restrict__ F, const float* __restrict__ scale,
                     const float* __restrict__ shift, float* __restrict__ out) {
  const int i4 = (blockIdx.x * 256 + threadIdx.x) << 2;
  const int c = (i4 >> 10) & 63;
  const float sc = scale[c], sh = shift[c];
  float4 v = *reinterpret_cast<const float4*>(F + i4);
  float4 o;
  o.x = fmaf(v.x, sc, sh); o.y = fmaf(v.y, sc, sh);
  o.z = fmaf(v.z, sc, sh); o.w = fmaf(v.w, sc, sh);
  *reinterpret_cast<float4*>(out + i4) = o;
}

__global__ void init_kernel(float* bsum) {
  int t = threadIdx.x;
  if (t < BATCH) bsum[t] = 0.f;
}

// ============================ host side =====================================
static void launch_conv_f(const float* X, const float* W, float* Y,
                          int Cin, int Cout, hipStream_t st) {
  dim3 g(16, BATCH);
  if (Cin == 128 && Cout == 128)
    conv_kernel<128, 8><<<g, 256, 0, st>>>(X, W, nullptr, Y, Cout);
  else if (Cin == 128 && Cout == 256)
    conv_kernel<128, 16><<<g, 256, 0, st>>>(X, W, nullptr, Y, Cout);
  else if (Cin == 256 && Cout == 256)
    conv_kernel<256, 16><<<g, 256, 0, st>>>(X, W, nullptr, Y, Cout);
  else if (Cin == 256 && Cout == 64)
    conv_kernel<256, 4><<<g, 256, 0, st>>>(X, W, nullptr, Y, Cout);
}

static void run_block(const float* x, int cin, int cout,
                      const float* w1, const float* s1, const float* b1,
                      const float* w2, const float* s2, const float* b2,
                      const float* wsw, const float* ssw, const float* bsw,
                      float* T1, float* T2, float* SC, float* O,
                      float* sc0, float* sh0, float* sc1, float* sh1,
                      hipStream_t st) {
  const int cm = cout - 1;
  const int gridE = BATCH * cout; // elements / 1024
  launch_conv_f(x, w1, T1, cin, cout, st);
  bn_stats_kernel<<<cout, 256, 0, st>>>(T1, s1, b1, sc0, sh0, cout);
  bn_relu_kernel<<<gridE, 256, 0, st>>>(T1, sc0, sh0, cm);
  launch_conv_f(T1, w2, T2, cout, cout, st);
  bn_stats_kernel<<<cout, 256, 0, st>>>(T2, s2, b2, sc0, sh0, cout);
  if (wsw) {
    launch_conv_f(x, wsw, SC, cin, cout, st);
    bn_stats_kernel<<<cout, 256, 0, st>>>(SC, ssw, bsw, sc1, sh1, cout);
    epil2_kernel<<<gridE, 256, 0, st>>>(T2, sc0, sh0, SC, sc1, sh1, O, cm);
  } else {
    epil_add_kernel<<<gridE, 256, 0, st>>>(T2, sc0, sh0, x, O, cm);
  }
}

extern "C" void kernel_launch(void* const* d_in, const int* in_sizes, int n_in,
                              void* d_out, int out_size, void* d_ws, size_t ws_size,
                              hipStream_t stream) {
  float* wsf = (float*)d_ws;
  const size_t M1 = (size_t)1 << 20;
  const size_t H1 = (size_t)1 << 19; // 0.5M

  // ---- workspace layout (floats) ----
  // phase 1: PAR[0,0.5M) XAF[0.5,1.5) XBF[1.5,2.5) QA[2.5,3.5) QB[3.5,4.5)
  //          KA[4.5,5.5) KB[5.5,6.5) XBA[6.5,7.5) XAA[7.5,8.5) YA[8.5,10.5) YB[10.5,12.5)
  // phase 2 (after concat, [0.5,8.5) dead): T1[0.5,4.5) SC[4.5,8.5) T2[12.5,16.5) O1[16.5,18.5)
  float* PAR = wsf;
  float* XAF = wsf + H1;
  float* XBF = wsf + H1 + 1 * M1;
  float* QA  = wsf + H1 + 2 * M1;
  float* QB  = wsf + H1 + 3 * M1;
  float* KA  = wsf + H1 + 4 * M1;
  float* KB  = wsf + H1 + 5 * M1;
  float* XBA = wsf + H1 + 6 * M1;
  float* XAA = wsf + H1 + 7 * M1;
  float* YA  = wsf + H1 + 8 * M1;
  float* YB  = wsf + H1 + 10 * M1;
  float* T1  = wsf + H1;            // over XAF..QB
  float* SC  = wsf + H1 + 4 * M1;   // over KA..XAA
  float* T2  = wsf + H1 + 12 * M1;
  float* O1  = wsf + H1 + 16 * M1;
  float* tail = wsf + H1 + 18 * M1;
  float* bsum = tail;
  float* sc0  = tail + 32;  float* sh0 = sc0 + 256;
  float* sc1  = sh0 + 256;  float* sh1 = sc1 + 256;
  int*   flag = (int*)(sh1 + 256);

  // ---- import all inputs to f32 ----
  ImportArgs ia;
  const float* pp[46];
  ia.p[0] = d_in[0]; ia.sz[0] = in_sizes[0]; ia.off[0] = (int)(H1);
  ia.p[1] = d_in[1]; ia.sz[1] = in_sizes[1]; ia.off[1] = (int)(H1 + M1);
  pp[0] = XAF; pp[1] = XBF;
  int run = 0;
  for (int i = 2; i < 46 && i < n_in; ++i) {
    ia.p[i] = d_in[i]; ia.sz[i] = in_sizes[i]; ia.off[i] = run;
    pp[i] = PAR + run;
    run += in_sizes[i];
  }

  detect_kernel<<<1, 256, 0, stream>>>((const unsigned*)d_in[0], flag);
  import_kernel<<<dim3(46, 16), 256, 0, stream>>>(ia, wsf, flag);
  init_kernel<<<1, 64, 0, stream>>>(bsum);

  // ---- q/k convs ----
  dim3 gq(16, BATCH);
  conv_kernel<64, 4><<<gq, 256, 0, stream>>>(XAF, pp[2], pp[3], QA, 64);
  conv_kernel<64, 4><<<gq, 256, 0, stream>>>(XBF, pp[4], pp[5], QB, 64);
  conv_kernel<64, 4><<<gq, 256, 0, stream>>>(XAF, pp[6], pp[7], KA, 64);
  conv_kernel<64, 4><<<gq, 256, 0, stream>>>(XBF, pp[8], pp[9], KB, 64);

  // ---- fused attention (no E materialization; softmax shift-invariant) ----
  fused_pv_kernel<<<dim3(16, BATCH), 256, 0, stream>>>(QA, QB, KB, XBA, bsum);
  fused_tpv_kernel<<<dim3(16, BATCH), 256, 0, stream>>>(QA, QB, KA, XAA);

  concat_kernel<<<8192, 256, 0, stream>>>(XAF, XBA, bsum, YA);
  concat_kernel<<<8192, 256, 0, stream>>>(XBF, XAA, bsum, YB);

  // ---- stream a ----
  run_block(YA, 128, 128, pp[10], pp[11], pp[12], pp[13], pp[14], pp[15],
            nullptr, nullptr, nullptr, T1, T2, SC, O1, sc0, sh0, sc1, sh1, stream);
  run_block(O1, 128, 256, pp[22], pp[23], pp[24], pp[25], pp[26], pp[27],
            pp[28], pp[29], pp[30], T1, T2, SC, /*O=*/T1, sc0, sh0, sc1, sh1, stream);
  launch_conv_f(T1, pp[40], T2, 256, 64, stream);
  bn_stats_kernel<<<64, 256, 0, stream>>>(T2, pp[41], pp[42], sc0, sh0, 64);
  writeout_kernel<<<1024, 256, 0, stream>>>(T2, sc0, sh0, (float*)d_out);

  // ---- stream b ----
  run_block(YB, 128, 128, pp[16], pp[17], pp[18], pp[19], pp[20], pp[21],
            nullptr, nullptr, nullptr, T1, T2, SC, O1, sc0, sh0, sc1, sh1, stream);
  run_block(O1, 128, 256, pp[31], pp[32], pp[33], pp[34], pp[35], pp[36],
            pp[37], pp[38], pp[39], T1, T2, SC, /*O=*/T1, sc0, sh0, sc1, sh1, stream);
  launch_conv_f(T1, pp[43], T2, 256, 64, stream);
  bn_stats_kernel<<<64, 256, 0, stream>>>(T2, pp[44], pp[45], sc0, sh0, 64);
  writeout_kernel<<<1024, 256, 0, stream>>>(T2, sc0, sh0, (float*)d_out + M1);
}

// Round 4
// 778.725 us; speedup vs baseline: 1.3287x; 1.3287x over previous
//
#include <hip/hip_runtime.h>
#include <hip/hip_bf16.h>
#include <cstddef>

static constexpr int BATCH = 16;   // B
static constexpr int NPIX  = 1024; // H*W

// ---------------- input dtype detection + import to f32 ---------------------
__global__ void detect_kernel(const unsigned* __restrict__ x, int* flag) {
  __shared__ int red[256];
  const int tid = threadIdx.x;
  int cnt = 0;
  for (int i = tid; i < 4096; i += 256) {
    unsigned e = (x[i] >> 7) & 0xFFu;
    cnt += (e >= 90u && e <= 135u) ? 1 : 0;
  }
  red[tid] = cnt; __syncthreads();
  for (int s = 128; s > 0; s >>= 1) {
    if (tid < s) red[tid] += red[tid + s];
    __syncthreads();
  }
  if (tid == 0) *flag = (red[0] > 3072) ? 1 : 0;  // 1 = bf16 layout
}

struct ImportArgs {
  const void* p[46];
  int sz[46];
  int off[46];
};

__global__ __launch_bounds__(256)
void import_kernel(ImportArgs a, float* __restrict__ wsf, const int* __restrict__ flag) {
  const int t = blockIdx.x;
  const int sz = a.sz[t];
  float* dst = wsf + a.off[t];
  const int isb = *flag;
  for (int i = blockIdx.y * 256 + threadIdx.x; i < sz; i += 16 * 256) {
    float v;
    if (isb) v = __uint_as_float((unsigned)((const unsigned short*)a.p[t])[i] << 16);
    else     v = ((const float*)a.p[t])[i];
    dst[i] = v;
  }
}

// zero bsum + stats regions
__global__ void init_kernel(float* __restrict__ tail, int n) {
  for (int i = threadIdx.x; i < n; i += 256) tail[i] = 0.f;
}

// ---------------- generalized conv1x1 ---------------------------------------
// MODE: 0 plain, 1 +bias, 2 pre-BN-relu on input, 3 virtual-concat input
// grid (Cout/OG, 2, B); 256 threads; 2 px per thread (float2), 512 px/block.
template<int CIN, int OG, int MODE, bool STATS>
__global__ __launch_bounds__(256)
void convg_kernel(const float* __restrict__ X0, const float* __restrict__ X1,
                  const float* __restrict__ W, const float* __restrict__ bias,
                  const float* __restrict__ prodSums, const float* __restrict__ gam,
                  const float* __restrict__ bet, const float* __restrict__ bsum,
                  float* __restrict__ Y, float* __restrict__ outSums, int Cout) {
  __shared__ float wsT[CIN][OG];
  __shared__ float scs[CIN];
  __shared__ float shs[CIN];
  __shared__ float sred[STATS ? 4 : 1][OG][2];
  constexpr int LOG = (OG == 4) ? 2 : 3;
  const int tid = threadIdx.x;
  const int o0 = blockIdx.x * OG;
  const int b  = blockIdx.z;
  const int px = (blockIdx.y << 9) + (tid << 1);

  float wscale1 = 1.f;
  if (MODE == 3) wscale1 = 1.f / bsum[b];
  for (int idx = tid; idx < CIN * OG; idx += 256) {
    int c = idx >> LOG, k = idx & (OG - 1);
    float w = W[(o0 + k) * CIN + c];
    if (MODE == 3 && c >= (CIN / 2)) w *= wscale1;
    wsT[c][k] = w;
  }
  if (MODE == 2) {
    const float invN = 1.f / 16384.f;
    for (int c = tid; c < CIN; c += 256) {
      float m  = prodSums[c] * invN;
      float vv = prodSums[256 + c] * invN - m * m;
      float sc = gam[c] * rsqrtf(vv + 1e-5f);
      scs[c] = sc;
      shs[c] = bet[c] - m * sc;
    }
  }
  __syncthreads();

  float acc[OG][2];
#pragma unroll
  for (int k = 0; k < OG; ++k) { acc[k][0] = 0.f; acc[k][1] = 0.f; }

  const float* xb0;
  const float* xb1 = nullptr;
  if (MODE == 3) {
    xb0 = X0 + (((size_t)b * 64) << 10);
    xb1 = X1 + (((size_t)b * 64) << 10);
  } else {
    xb0 = X0 + (((size_t)b * CIN) << 10);
  }

#pragma unroll 4
  for (int c = 0; c < CIN; ++c) {
    float2 xv;
    if (MODE == 3) {
      const float* src = (c < CIN / 2) ? (xb0 + (c << 10))
                                       : (xb1 + ((c - CIN / 2) << 10));
      xv = *reinterpret_cast<const float2*>(src + px);
    } else {
      xv = *reinterpret_cast<const float2*>(xb0 + (c << 10) + px);
    }
    if (MODE == 2) {
      xv.x = fmaxf(fmaf(xv.x, scs[c], shs[c]), 0.f);
      xv.y = fmaxf(fmaf(xv.y, scs[c], shs[c]), 0.f);
    }
    const float4* wrow = reinterpret_cast<const float4*>(wsT[c]);
    float4 wa = wrow[0];
    acc[0][0] = fmaf(wa.x, xv.x, acc[0][0]); acc[0][1] = fmaf(wa.x, xv.y, acc[0][1]);
    acc[1][0] = fmaf(wa.y, xv.x, acc[1][0]); acc[1][1] = fmaf(wa.y, xv.y, acc[1][1]);
    acc[2][0] = fmaf(wa.z, xv.x, acc[2][0]); acc[2][1] = fmaf(wa.z, xv.y, acc[2][1]);
    acc[3][0] = fmaf(wa.w, xv.x, acc[3][0]); acc[3][1] = fmaf(wa.w, xv.y, acc[3][1]);
    if (OG == 8) {
      float4 wb = wrow[1];
      acc[4][0] = fmaf(wb.x, xv.x, acc[4][0]); acc[4][1] = fmaf(wb.x, xv.y, acc[4][1]);
      acc[5][0] = fmaf(wb.y, xv.x, acc[5][0]); acc[5][1] = fmaf(wb.y, xv.y, acc[5][1]);
      acc[6][0] = fmaf(wb.z, xv.x, acc[6][0]); acc[6][1] = fmaf(wb.z, xv.y, acc[6][1]);
      acc[7][0] = fmaf(wb.w, xv.x, acc[7][0]); acc[7][1] = fmaf(wb.w, xv.y, acc[7][1]);
    }
  }

#pragma unroll
  for (int k = 0; k < OG; ++k) {
    float2 o;
    float bv = (MODE == 1) ? bias[o0 + k] : 0.f;
    o.x = acc[k][0] + bv; o.y = acc[k][1] + bv;
    *reinterpret_cast<float2*>(Y + (((size_t)(b * Cout + o0 + k)) << 10) + px) = o;
  }

  if (STATS) {
    const int lane = tid & 63, wv = tid >> 6;
#pragma unroll
    for (int k = 0; k < OG; ++k) {
      float s = acc[k][0] + acc[k][1];
      float q = acc[k][0] * acc[k][0] + acc[k][1] * acc[k][1];
      for (int off = 32; off; off >>= 1) {
        s += __shfl_down(s, off);
        q += __shfl_down(q, off);
      }
      if (lane == 0) { sred[wv][k][0] = s; sred[wv][k][1] = q; }
    }
    __syncthreads();
    if (tid < OG) {
      float s = sred[0][tid][0] + sred[1][tid][0] + sred[2][tid][0] + sred[3][tid][0];
      float q = sred[0][tid][1] + sred[1][tid][1] + sred[2][tid][1] + sred[3][tid][1];
      atomicAdd(&outSums[o0 + tid], s);
      atomicAdd(&outSums[256 + o0 + tid], q);
    }
  }
}

// ---- fused PV partial: PART[js][b,c,i] = sum_{j in chunk} exp(-E) KB[c,j] ---
__global__ __launch_bounds__(256)
void fused_pv_kernel(const float* __restrict__ QA, const float* __restrict__ QB,
                     const float* __restrict__ KB, float* __restrict__ PART,
                     float* __restrict__ bsum) {
  __shared__ float U[64][64];
  __shared__ float V[64][65];
  __shared__ float W[64][65];
  __shared__ float red[256];
  const int tid = threadIdx.x;
  const int b = blockIdx.z, i0 = blockIdx.x << 6;
  const int jbase = blockIdx.y << 8;  // 256 j per block
  const int tx = tid & 15, ty = tid >> 4;
  const float* qa = QA + ((size_t)b << 16);
  const float* qb = QB + ((size_t)b << 16);
  const float* kb = KB + ((size_t)b << 16);
  float* OUT = PART + ((size_t)blockIdx.y << 20);
  for (int idx = tid; idx < 4096; idx += 256) {
    int c = idx >> 6, x = idx & 63;
    U[c][x] = qa[(c << 10) + i0 + x];
  }
  float accO[4][4] = {};
  float psum = 0.f;
  for (int jt = 0; jt < 4; ++jt) {
    const int j0 = jbase + (jt << 6);
    __syncthreads();
    for (int idx = tid; idx < 4096; idx += 256) {
      int c = idx >> 6, x = idx & 63;
      V[c][x] = qb[(c << 10) + j0 + x];
    }
    __syncthreads();
    float e[4][4] = {};
#pragma unroll 4
    for (int c = 0; c < 64; ++c) {
      float a[4], bb[4];
#pragma unroll
      for (int p = 0; p < 4; ++p) a[p] = U[c][(ty << 2) + p];
#pragma unroll
      for (int q = 0; q < 4; ++q) bb[q] = V[c][(tx << 2) + q];
#pragma unroll
      for (int p = 0; p < 4; ++p)
#pragma unroll
        for (int q = 0; q < 4; ++q) e[p][q] = fmaf(a[p], bb[q], e[p][q]);
    }
    __syncthreads();
#pragma unroll
    for (int p = 0; p < 4; ++p)
#pragma unroll
      for (int q = 0; q < 4; ++q) {
        float pv = __expf(-e[p][q]);
        psum += pv;
        W[(ty << 2) + p][(tx << 2) + q] = pv;
      }
    for (int idx = tid; idx < 4096; idx += 256) {
      int c = idx >> 6, x = idx & 63;
      V[c][x] = kb[(c << 10) + j0 + x];
    }
    __syncthreads();
#pragma unroll 4
    for (int j = 0; j < 64; ++j) {
      float kv[4], pw[4];
#pragma unroll
      for (int k = 0; k < 4; ++k) kv[k] = V[(ty << 2) + k][j];
#pragma unroll
      for (int p = 0; p < 4; ++p) pw[p] = W[(tx << 2) + p][j];
#pragma unroll
      for (int k = 0; k < 4; ++k)
#pragma unroll
        for (int p = 0; p < 4; ++p) accO[k][p] = fmaf(kv[k], pw[p], accO[k][p]);
    }
  }
#pragma unroll
  for (int k = 0; k < 4; ++k)
#pragma unroll
    for (int p = 0; p < 4; ++p)
      OUT[((size_t)(b * 64 + (ty << 2) + k) << 10) + i0 + (tx << 2) + p] = accO[k][p];
  red[tid] = psum; __syncthreads();
  for (int s = 128; s > 0; s >>= 1) {
    if (tid < s) red[tid] += red[tid + s];
    __syncthreads();
  }
  if (tid == 0) atomicAdd(bsum + b, red[0]);
}

// ---- fused PtV partial: PART[is][b,c,j] = sum_{i in chunk} exp(-E) KA[c,i] --
__global__ __launch_bounds__(256)
void fused_tpv_kernel(const float* __restrict__ QA, const float* __restrict__ QB,
                      const float* __restrict__ KA, float* __restrict__ PART) {
  __shared__ float U[64][64];
  __shared__ float V[64][65];
  __shared__ float W[64][65];
  const int tid = threadIdx.x;
  const int b = blockIdx.z, j0 = blockIdx.x << 6;
  const int ibase = blockIdx.y << 8;
  const int tx = tid & 15, ty = tid >> 4;
  const float* qa = QA + ((size_t)b << 16);
  const float* qb = QB + ((size_t)b << 16);
  const float* ka = KA + ((size_t)b << 16);
  float* OUT = PART + ((size_t)blockIdx.y << 20);
  for (int idx = tid; idx < 4096; idx += 256) {
    int c = idx >> 6, x = idx & 63;
    U[c][x] = qb[(c << 10) + j0 + x];
  }
  float accO[4][4] = {};
  for (int it = 0; it < 4; ++it) {
    const int i0 = ibase + (it << 6);
    __syncthreads();
    for (int idx = tid; idx < 4096; idx += 256) {
      int c = idx >> 6, x = idx & 63;
      V[c][x] = qa[(c << 10) + i0 + x];
    }
    __syncthreads();
    float e[4][4] = {};   // i = ty4+p, j = tx4+q
#pragma unroll 4
    for (int c = 0; c < 64; ++c) {
      float a[4], bb[4];
#pragma unroll
      for (int p = 0; p < 4; ++p) a[p] = V[c][(ty << 2) + p];
#pragma unroll
      for (int q = 0; q < 4; ++q) bb[q] = U[c][(tx << 2) + q];
#pragma unroll
      for (int p = 0; p < 4; ++p)
#pragma unroll
        for (int q = 0; q < 4; ++q) e[p][q] = fmaf(a[p], bb[q], e[p][q]);
    }
    __syncthreads();
#pragma unroll
    for (int p = 0; p < 4; ++p)
#pragma unroll
      for (int q = 0; q < 4; ++q)
        W[(ty << 2) + p][(tx << 2) + q] = __expf(-e[p][q]);
    for (int idx = tid; idx < 4096; idx += 256) {
      int c = idx >> 6, x = idx & 63;
      V[c][x] = ka[(c << 10) + i0 + x];
    }
    __syncthreads();
#pragma unroll 4
    for (int i = 0; i < 64; ++i) {
      float kv[4], pw[4];
#pragma unroll
      for (int k = 0; k < 4; ++k) kv[k] = V[(ty << 2) + k][i];
#pragma unroll
      for (int p = 0; p < 4; ++p) pw[p] = W[i][(tx << 2) + p];
#pragma unroll
      for (int k = 0; k < 4; ++k)
#pragma unroll
        for (int p = 0; p < 4; ++p) accO[k][p] = fmaf(kv[k], pw[p], accO[k][p]);
    }
  }
#pragma unroll
  for (int k = 0; k < 4; ++k)
#pragma unroll
    for (int p = 0; p < 4; ++p)
      OUT[((size_t)(b * 64 + (ty << 2) + k) << 10) + j0 + (tx << 2) + p] = accO[k][p];
}

// ---- sum 4 partials ---------------------------------------------------------
__global__ __launch_bounds__(256)
void part_reduce_kernel(const float* __restrict__ P, float* __restrict__ O) {
  const size_t i4 = ((size_t)blockIdx.x * 256 + threadIdx.x) << 2;
  float4 a = *reinterpret_cast<const float4*>(P + i4);
  float4 b = *reinterpret_cast<const float4*>(P + (1u << 20) + i4);
  float4 c = *reinterpret_cast<const float4*>(P + (2u << 20) + i4);
  float4 d = *reinterpret_cast<const float4*>(P + (3u << 20) + i4);
  float4 o;
  o.x = (a.x + b.x) + (c.x + d.x);
  o.y = (a.y + b.y) + (c.y + d.y);
  o.z = (a.z + b.z) + (c.z + d.z);
  o.w = (a.w + b.w) + (c.w + d.w);
  *reinterpret_cast<float4*>(O + i4) = o;
}

// ---------------- O = relu(bn(T) + concat-residual) -------------------------
__global__ __launch_bounds__(256)
void epil_add_kernel(const float* __restrict__ T, const float* __restrict__ sums,
                     const float* __restrict__ gam, const float* __restrict__ bet,
                     const float* __restrict__ XR, const float* __restrict__ ATT,
                     const float* __restrict__ bsum, float* __restrict__ O) {
  const int i4 = (blockIdx.x * 256 + threadIdx.x) << 2;
  const int c = (i4 >> 10) & 127;
  const int b = i4 >> 17;
  const int n = i4 & 1023;
  const float invN = 1.f / 16384.f;
  float m  = sums[c] * invN;
  float vv = sums[256 + c] * invN - m * m;
  float sc = gam[c] * rsqrtf(vv + 1e-5f);
  float sh = bet[c] - m * sc;
  float4 t = *reinterpret_cast<const float4*>(T + i4);
  float4 r;
  if (c < 64) {
    r = *reinterpret_cast<const float4*>(XR + (((size_t)(b * 64 + c)) << 10) + n);
  } else {
    r = *reinterpret_cast<const float4*>(ATT + (((size_t)(b * 64 + c - 64)) << 10) + n);
    float inv = 1.f / bsum[b];
    r.x *= inv; r.y *= inv; r.z *= inv; r.w *= inv;
  }
  float4 o;
  o.x = fmaxf(fmaf(t.x, sc, sh) + r.x, 0.f);
  o.y = fmaxf(fmaf(t.y, sc, sh) + r.y, 0.f);
  o.z = fmaxf(fmaf(t.z, sc, sh) + r.z, 0.f);
  o.w = fmaxf(fmaf(t.w, sc, sh) + r.w, 0.f);
  *reinterpret_cast<float4*>(O + i4) = o;
}

// ---------------- O = relu(bn0(T) + bn1(S)) ---------------------------------
__global__ __launch_bounds__(256)
void epil2_kernel(const float* __restrict__ T, const float* __restrict__ sums0,
                  const float* __restrict__ g0, const float* __restrict__ b0,
                  const float* __restrict__ S, const float* __restrict__ sums1,
                  const float* __restrict__ g1, const float* __restrict__ b1,
                  float* __restrict__ O) {
  const int i4 = (blockIdx.x * 256 + threadIdx.x) << 2;
  const int c = (i4 >> 10) & 255;
  const float invN = 1.f / 16384.f;
  float m0 = sums0[c] * invN;
  float v0 = sums0[256 + c] * invN - m0 * m0;
  float a0 = g0[c] * rsqrtf(v0 + 1e-5f);
  float h0 = b0[c] - m0 * a0;
  float m1 = sums1[c] * invN;
  float v1 = sums1[256 + c] * invN - m1 * m1;
  float a1 = g1[c] * rsqrtf(v1 + 1e-5f);
  float h1 = b1[c] - m1 * a1;
  float4 t = *reinterpret_cast<const float4*>(T + i4);
  float4 s = *reinterpret_cast<const float4*>(S + i4);
  float4 o;
  o.x = fmaxf(fmaf(t.x, a0, h0) + fmaf(s.x, a1, h1), 0.f);
  o.y = fmaxf(fmaf(t.y, a0, h0) + fmaf(s.y, a1, h1), 0.f);
  o.z = fmaxf(fmaf(t.z, a0, h0) + fmaf(s.z, a1, h1), 0.f);
  o.w = fmaxf(fmaf(t.w, a0, h0) + fmaf(s.w, a1, h1), 0.f);
  *reinterpret_cast<float4*>(O + i4) = o;
}

// ---------------- final: out = bn(F) as f32 ---------------------------------
__global__ __launch_bounds__(256)
void writeout_kernel(const float* __restrict__ F, const float* __restrict__ sums,
                     const float* __restrict__ gam, const float* __restrict__ bet,
                     float* __restrict__ out) {
  const int i4 = (blockIdx.x * 256 + threadIdx.x) << 2;
  const int c = (i4 >> 10) & 63;
  const float invN = 1.f / 16384.f;
  float m  = sums[c] * invN;
  float vv = sums[256 + c] * invN - m * m;
  float sc = gam[c] * rsqrtf(vv + 1e-5f);
  float sh = bet[c] - m * sc;
  float4 v = *reinterpret_cast<const float4*>(F + i4);
  float4 o;
  o.x = fmaf(v.x, sc, sh); o.y = fmaf(v.y, sc, sh);
  o.z = fmaf(v.z, sc, sh); o.w = fmaf(v.w, sc, sh);
  *reinterpret_cast<float4*>(out + i4) = o;
}

// ============================ host side =====================================
extern "C" void kernel_launch(void* const* d_in, const int* in_sizes, int n_in,
                              void* d_out, int out_size, void* d_ws, size_t ws_size,
                              hipStream_t stream) {
  float* wsf = (float*)d_ws;
  const size_t M1 = (size_t)1 << 20;
  const size_t H1 = (size_t)1 << 19;

  float* PAR = wsf;                    // 0.5M params
  float* XAF = wsf + H1;               // 1M
  float* XBF = wsf + H1 + 1 * M1;      // 1M
  float* R0  = wsf + H1 + 2 * M1;      // 4M  (QA, QB)
  float* R1  = wsf + H1 + 6 * M1;      // 4M  (KA, KB)
  float* XBA = wsf + H1 + 10 * M1;     // 1M
  float* XAA = wsf + H1 + 11 * M1;     // 1M
  float* R2  = wsf + H1 + 12 * M1;     // 4M  (PART, then SC)
  float* O1  = wsf + H1 + 16 * M1;     // 2M
  float* tail = wsf + H1 + 18 * M1;
  float* bsum  = tail;                 // 16
  float* stats = tail + 16;            // 12 * 512
  int*   flag  = (int*)(tail + 16 + 12 * 512);

  float* QA = R0;           float* QB = R0 + M1;
  float* KA = R1;           float* KB = R1 + M1;

  // ---- import all inputs to f32 ----
  ImportArgs ia;
  const float* pp[46];
  ia.p[0] = d_in[0]; ia.sz[0] = in_sizes[0]; ia.off[0] = (int)(H1);
  ia.p[1] = d_in[1]; ia.sz[1] = in_sizes[1]; ia.off[1] = (int)(H1 + M1);
  pp[0] = XAF; pp[1] = XBF;
  int run = 0;
  for (int i = 2; i < 46 && i < n_in; ++i) {
    ia.p[i] = d_in[i]; ia.sz[i] = in_sizes[i]; ia.off[i] = run;
    pp[i] = PAR + run;
    run += in_sizes[i];
  }

  detect_kernel<<<1, 256, 0, stream>>>((const unsigned*)d_in[0], flag);
  import_kernel<<<dim3(46, 16), 256, 0, stream>>>(ia, wsf, flag);
  init_kernel<<<1, 256, 0, stream>>>(tail, 16 + 12 * 512);

  float* ST[12];
  for (int i = 0; i < 12; ++i) ST[i] = stats + i * 512;

  // ---- q/k convs (bias) ----
  dim3 gq(16, 2, BATCH);
  convg_kernel<64, 4, 1, false><<<gq, 256, 0, stream>>>(XAF, nullptr, pp[2], pp[3],
      nullptr, nullptr, nullptr, nullptr, QA, nullptr, 64);
  convg_kernel<64, 4, 1, false><<<gq, 256, 0, stream>>>(XBF, nullptr, pp[4], pp[5],
      nullptr, nullptr, nullptr, nullptr, QB, nullptr, 64);
  convg_kernel<64, 4, 1, false><<<gq, 256, 0, stream>>>(XAF, nullptr, pp[6], pp[7],
      nullptr, nullptr, nullptr, nullptr, KA, nullptr, 64);
  convg_kernel<64, 4, 1, false><<<gq, 256, 0, stream>>>(XBF, nullptr, pp[8], pp[9],
      nullptr, nullptr, nullptr, nullptr, KB, nullptr, 64);

  // ---- attention (split 4-way, partials in R2) ----
  fused_pv_kernel<<<dim3(16, 4, BATCH), 256, 0, stream>>>(QA, QB, KB, R2, bsum);
  part_reduce_kernel<<<1024, 256, 0, stream>>>(R2, XBA);
  fused_tpv_kernel<<<dim3(16, 4, BATCH), 256, 0, stream>>>(QA, QB, KA, R2);
  part_reduce_kernel<<<1024, 256, 0, stream>>>(R2, XAA);

  for (int sbi = 0; sbi < 2; ++sbi) {
    const float* XR  = sbi ? XBF : XAF;
    const float* ATT = sbi ? XAA : XBA;
    const int base1 = sbi ? 16 : 10;   // b1 : a1 params
    const int base2 = sbi ? 31 : 22;   // b2 : a2 params
    const int baseo = sbi ? 43 : 40;   // ob : oa params
    float* s_t1a = ST[sbi * 6 + 0];
    float* s_t2a = ST[sbi * 6 + 1];
    float* s_t1b = ST[sbi * 6 + 2];
    float* s_t2b = ST[sbi * 6 + 3];
    float* s_sc  = ST[sbi * 6 + 4];
    float* s_o   = ST[sbi * 6 + 5];

    // ---- block 1 (128 -> 128) ----
    convg_kernel<128, 8, 3, true><<<dim3(16, 2, BATCH), 256, 0, stream>>>(
        XR, ATT, pp[base1 + 0], nullptr, nullptr, nullptr, nullptr, bsum, R0, s_t1a, 128);
    convg_kernel<128, 8, 2, true><<<dim3(16, 2, BATCH), 256, 0, stream>>>(
        R0, nullptr, pp[base1 + 3], nullptr, s_t1a, pp[base1 + 1], pp[base1 + 2], nullptr,
        R1, s_t2a, 128);
    epil_add_kernel<<<BATCH * 128, 256, 0, stream>>>(
        R1, s_t2a, pp[base1 + 4], pp[base1 + 5], XR, ATT, bsum, O1);

    // ---- block 2 (128 -> 256, with shortcut) ----
    convg_kernel<128, 8, 0, true><<<dim3(32, 2, BATCH), 256, 0, stream>>>(
        O1, nullptr, pp[base2 + 0], nullptr, nullptr, nullptr, nullptr, nullptr,
        R0, s_t1b, 256);
    convg_kernel<256, 8, 2, true><<<dim3(32, 2, BATCH), 256, 0, stream>>>(
        R0, nullptr, pp[base2 + 3], nullptr, s_t1b, pp[base2 + 1], pp[base2 + 2], nullptr,
        R1, s_t2b, 256);
    convg_kernel<128, 8, 0, true><<<dim3(32, 2, BATCH), 256, 0, stream>>>(
        O1, nullptr, pp[base2 + 6], nullptr, nullptr, nullptr, nullptr, nullptr,
        R2, s_sc, 256);
    epil2_kernel<<<BATCH * 256, 256, 0, stream>>>(
        R1, s_t2b, pp[base2 + 4], pp[base2 + 5], R2, s_sc, pp[base2 + 7], pp[base2 + 8], R0);

    // ---- output conv (256 -> 64) + BN ----
    convg_kernel<256, 4, 0, true><<<dim3(16, 2, BATCH), 256, 0, stream>>>(
        R0, nullptr, pp[baseo + 0], nullptr, nullptr, nullptr, nullptr, nullptr,
        R1, s_o, 64);
    writeout_kernel<<<1024, 256, 0, stream>>>(
        R1, s_o, pp[baseo + 1], pp[baseo + 2], (float*)d_out + sbi * M1);
  }
}

// Round 5
// 546.672 us; speedup vs baseline: 1.8928x; 1.4245x over previous
//
#include <hip/hip_runtime.h>
#include <hip/hip_bf16.h>
#include <cstddef>

static constexpr int BATCH = 16;   // B
static constexpr int NPIX  = 1024; // H*W

typedef __attribute__((ext_vector_type(8))) short bf16x8;
typedef __attribute__((ext_vector_type(4))) float f32x4;

__device__ __forceinline__ unsigned short f2bf(float f) {
  unsigned u = __float_as_uint(f);
  unsigned r = (u + 0x7fffu + ((u >> 16) & 1u)) >> 16;  // RNE
  return (unsigned short)r;
}

// ---------------- input dtype detection + import to f32 ---------------------
__global__ void detect_kernel(const unsigned* __restrict__ x, int* flag) {
  __shared__ int red[256];
  const int tid = threadIdx.x;
  int cnt = 0;
  for (int i = tid; i < 4096; i += 256) {
    unsigned e = (x[i] >> 7) & 0xFFu;
    cnt += (e >= 90u && e <= 135u) ? 1 : 0;
  }
  red[tid] = cnt; __syncthreads();
  for (int s = 128; s > 0; s >>= 1) {
    if (tid < s) red[tid] += red[tid + s];
    __syncthreads();
  }
  if (tid == 0) *flag = (red[0] > 3072) ? 1 : 0;
}

struct ImportArgs {
  const void* p[46];
  int sz[46];
  int off[46];
};

__global__ __launch_bounds__(256)
void import_kernel(ImportArgs a, float* __restrict__ wsf, const int* __restrict__ flag) {
  const int t = blockIdx.x;
  const int sz = a.sz[t];
  float* dst = wsf + a.off[t];
  const int isb = *flag;
  for (int i = blockIdx.y * 256 + threadIdx.x; i < sz; i += 16 * 256) {
    float v;
    if (isb) v = __uint_as_float((unsigned)((const unsigned short*)a.p[t])[i] << 16);
    else     v = ((const float*)a.p[t])[i];
    dst[i] = v;
  }
}

__global__ void init_kernel(float* __restrict__ tail, int n) {
  for (int i = threadIdx.x; i < n; i += 256) tail[i] = 0.f;
}

// ---------------- q/k conv: f32 [b][c][n] -> bf16, dual layouts -------------
// TR=0: Yt[b][n][64c]  (Q operands).  TR=1: Yc[b][c][n]  (K operands).
template<int TR>
__global__ __launch_bounds__(256)
void conv_qk_kernel(const float* __restrict__ X, const float* __restrict__ W,
                    const float* __restrict__ bias, unsigned short* __restrict__ Y) {
  __shared__ float wsT[64][4];
  const int tid = threadIdx.x;
  const int o0 = blockIdx.x << 2;
  const int b  = blockIdx.z;
  const int px = (blockIdx.y << 9) + (tid << 1);
  {
    int c = tid >> 2, k = tid & 3;
    wsT[c][k] = W[((o0 + k) << 6) + c];
  }
  __syncthreads();
  float acc[4][2] = {};
  const float* xb = X + ((size_t)b << 16) + px;
#pragma unroll 4
  for (int c = 0; c < 64; ++c) {
    float2 xv = *reinterpret_cast<const float2*>(xb + (c << 10));
    float4 w = *reinterpret_cast<const float4*>(wsT[c]);
    acc[0][0] = fmaf(w.x, xv.x, acc[0][0]); acc[0][1] = fmaf(w.x, xv.y, acc[0][1]);
    acc[1][0] = fmaf(w.y, xv.x, acc[1][0]); acc[1][1] = fmaf(w.y, xv.y, acc[1][1]);
    acc[2][0] = fmaf(w.z, xv.x, acc[2][0]); acc[2][1] = fmaf(w.z, xv.y, acc[2][1]);
    acc[3][0] = fmaf(w.w, xv.x, acc[3][0]); acc[3][1] = fmaf(w.w, xv.y, acc[3][1]);
  }
  float b0 = bias[o0], b1 = bias[o0 + 1], b2 = bias[o0 + 2], b3 = bias[o0 + 3];
  if (TR == 0) {
    ushort4 v0, v1;
    v0.x = f2bf(acc[0][0] + b0); v0.y = f2bf(acc[1][0] + b1);
    v0.z = f2bf(acc[2][0] + b2); v0.w = f2bf(acc[3][0] + b3);
    v1.x = f2bf(acc[0][1] + b0); v1.y = f2bf(acc[1][1] + b1);
    v1.z = f2bf(acc[2][1] + b2); v1.w = f2bf(acc[3][1] + b3);
    unsigned short* yt = Y + ((size_t)b << 16) + ((size_t)px << 6) + o0;
    *reinterpret_cast<ushort4*>(yt) = v0;
    *reinterpret_cast<ushort4*>(yt + 64) = v1;
  } else {
    float bv[4] = {b0, b1, b2, b3};
#pragma unroll
    for (int k = 0; k < 4; ++k) {
      ushort2 v;
      v.x = f2bf(acc[k][0] + bv[k]); v.y = f2bf(acc[k][1] + bv[k]);
      *reinterpret_cast<ushort2*>(Y + ((size_t)b << 16) + ((size_t)(o0 + k) << 10) + px) = v;
    }
  }
}

// ---- MFMA fused PV: PART[jc][b,c,i] = sum_{j in chunk} exp(-E[i,j]) KB[c,j] -
// E[i,j] = sum_c QA[c,i] QB[c,j].  grid (16 i-tiles, 4 j-chunks, B).
__global__ __launch_bounds__(256)
void pv_mfma_kernel(const unsigned short* __restrict__ QAt,
                    const unsigned short* __restrict__ QBt,
                    const unsigned short* __restrict__ KBc,
                    float* __restrict__ PART, float* __restrict__ bsum) {
  __shared__ __align__(16) unsigned short Ai[4096];  // QA tile [i][c] swz
  __shared__ __align__(16) unsigned short Bj[4096];  // QB tile [j][c] swz
  __shared__ __align__(16) unsigned short Pl[4096];  // P tile [i][j] swz
  __shared__ float red[256];
  const int tid = threadIdx.x;
  const int lane = tid & 63, w = tid >> 6;
  const int g = lane >> 4, m = lane & 15;
  const int i0 = blockIdx.x << 6;
  const int jbase = blockIdx.y << 8;
  const int b = blockIdx.z;
  const size_t nb = (size_t)b << 16;

  {
    const unsigned short* src = QAt + nb + ((size_t)i0 << 6);
#pragma unroll
    for (int s = 0; s < 2; ++s) {
      int idx = tid + (s << 8);
      int n = idx >> 3, cc = idx & 7;
      bf16x8 v = *reinterpret_cast<const bf16x8*>(src + (n << 6) + ((cc ^ (n & 7)) << 3));
      *reinterpret_cast<bf16x8*>(Ai + (idx << 3)) = v;
    }
  }
  f32x4 accO[4];
#pragma unroll
  for (int n = 0; n < 4; ++n) accO[n] = (f32x4){0.f, 0.f, 0.f, 0.f};
  float psum = 0.f;

  for (int jt = 0; jt < 4; ++jt) {
    const int j0 = jbase + (jt << 6);
    __syncthreads();
    {
      const unsigned short* src = QBt + nb + ((size_t)j0 << 6);
#pragma unroll
      for (int s = 0; s < 2; ++s) {
        int idx = tid + (s << 8);
        int n = idx >> 3, cc = idx & 7;
        bf16x8 v = *reinterpret_cast<const bf16x8*>(src + (n << 6) + ((cc ^ (n & 7)) << 3));
        *reinterpret_cast<bf16x8*>(Bj + (idx << 3)) = v;
      }
    }
    __syncthreads();
    // E phase: D[j,i]; wave w owns j-rows w*16..w*16+15
    const int jrow = (w << 4) | m;
    bf16x8 a0 = *reinterpret_cast<const bf16x8*>(Bj + (jrow << 6) + ((g ^ (jrow & 7)) << 3));
    bf16x8 a1 = *reinterpret_cast<const bf16x8*>(Bj + (jrow << 6) + (((g + 4) ^ (jrow & 7)) << 3));
    f32x4 e[4];
#pragma unroll
    for (int n = 0; n < 4; ++n) {
      const int irow = (n << 4) | m;
      bf16x8 b0v = *reinterpret_cast<const bf16x8*>(Ai + (irow << 6) + ((g ^ (irow & 7)) << 3));
      bf16x8 b1v = *reinterpret_cast<const bf16x8*>(Ai + (irow << 6) + (((g + 4) ^ (irow & 7)) << 3));
      e[n] = (f32x4){0.f, 0.f, 0.f, 0.f};
      e[n] = __builtin_amdgcn_mfma_f32_16x16x32_bf16(a0, b0v, e[n], 0, 0, 0);
      e[n] = __builtin_amdgcn_mfma_f32_16x16x32_bf16(a1, b1v, e[n], 0, 0, 0);
    }
    // exp + pack to Pl[i][j]; lane: i = n*16+m, j = w*16+g*4+r
    const int j = (w << 4) | (g << 2);
#pragma unroll
    for (int n = 0; n < 4; ++n) {
      const int irow = (n << 4) | m;
      float p0 = __expf(-e[n][0]), p1 = __expf(-e[n][1]);
      float p2 = __expf(-e[n][2]), p3 = __expf(-e[n][3]);
      psum += (p0 + p1) + (p2 + p3);
      unsigned pk01 = (unsigned)f2bf(p0) | ((unsigned)f2bf(p1) << 16);
      unsigned pk23 = (unsigned)f2bf(p2) | ((unsigned)f2bf(p3) << 16);
      int base = irow << 6;
      int off0 = base + ((((j) >> 3) ^ (irow & 7)) << 3) + (j & 7);
      int off2 = base + ((((j + 2) >> 3) ^ (irow & 7)) << 3) + ((j + 2) & 7);
      *reinterpret_cast<unsigned*>(Pl + off0) = pk01;
      *reinterpret_cast<unsigned*>(Pl + off2) = pk23;
    }
    // KB A-frags (global, [c][n] layout)
    const int crow = (w << 4) | m;
    const unsigned short* kbp = KBc + nb + ((size_t)crow << 10) + j0 + (g << 3);
    bf16x8 ka0 = *reinterpret_cast<const bf16x8*>(kbp);
    bf16x8 ka1 = *reinterpret_cast<const bf16x8*>(kbp + 32);
    __syncthreads();
    // PV: D[c,i] += KB(c,j) * P(j,i)
#pragma unroll
    for (int n = 0; n < 4; ++n) {
      const int irow = (n << 4) | m;
      bf16x8 p0 = *reinterpret_cast<const bf16x8*>(Pl + (irow << 6) + ((g ^ (irow & 7)) << 3));
      bf16x8 p1 = *reinterpret_cast<const bf16x8*>(Pl + (irow << 6) + (((g + 4) ^ (irow & 7)) << 3));
      accO[n] = __builtin_amdgcn_mfma_f32_16x16x32_bf16(ka0, p0, accO[n], 0, 0, 0);
      accO[n] = __builtin_amdgcn_mfma_f32_16x16x32_bf16(ka1, p1, accO[n], 0, 0, 0);
    }
  }
  // OUT: c = w*16 + g*4 + r, i = i0 + n*16 + m
  float* OUT = PART + ((size_t)blockIdx.y << 20) + (nb << 6 >> 6 << 0) + ((size_t)(b * 64) << 10);
#pragma unroll
  for (int n = 0; n < 4; ++n) {
    const int ig = i0 + (n << 4) + m;
    const int c = (w << 4) + (g << 2);
#pragma unroll
    for (int r = 0; r < 4; ++r)
      OUT[((size_t)(c + r) << 10) + ig] = accO[n][r];
  }
  red[tid] = psum; __syncthreads();
  for (int s = 128; s > 0; s >>= 1) {
    if (tid < s) red[tid] += red[tid + s];
    __syncthreads();
  }
  if (tid == 0) atomicAdd(bsum + b, red[0]);
}

// ---- MFMA fused PtV: PART[ic][b,c,j] = sum_{i in chunk} exp(-E[i,j]) KA[c,i]
__global__ __launch_bounds__(256)
void tpv_mfma_kernel(const unsigned short* __restrict__ QAt,
                     const unsigned short* __restrict__ QBt,
                     const unsigned short* __restrict__ KAc,
                     float* __restrict__ PART) {
  __shared__ __align__(16) unsigned short Bj[4096];  // QB tile [j][c] swz (persistent)
  __shared__ __align__(16) unsigned short Ai[4096];  // QA tile [i][c] swz
  __shared__ __align__(16) unsigned short Pl[4096];  // P tile [j][i] swz
  const int tid = threadIdx.x;
  const int lane = tid & 63, w = tid >> 6;
  const int g = lane >> 4, m = lane & 15;
  const int j0 = blockIdx.x << 6;
  const int ibase = blockIdx.y << 8;
  const int b = blockIdx.z;
  const size_t nb = (size_t)b << 16;

  {
    const unsigned short* src = QBt + nb + ((size_t)j0 << 6);
#pragma unroll
    for (int s = 0; s < 2; ++s) {
      int idx = tid + (s << 8);
      int n = idx >> 3, cc = idx & 7;
      bf16x8 v = *reinterpret_cast<const bf16x8*>(src + (n << 6) + ((cc ^ (n & 7)) << 3));
      *reinterpret_cast<bf16x8*>(Bj + (idx << 3)) = v;
    }
  }
  f32x4 accO[4];
#pragma unroll
  for (int n = 0; n < 4; ++n) accO[n] = (f32x4){0.f, 0.f, 0.f, 0.f};

  for (int it = 0; it < 4; ++it) {
    const int i0 = ibase + (it << 6);
    __syncthreads();
    {
      const unsigned short* src = QAt + nb + ((size_t)i0 << 6);
#pragma unroll
      for (int s = 0; s < 2; ++s) {
        int idx = tid + (s << 8);
        int n = idx >> 3, cc = idx & 7;
        bf16x8 v = *reinterpret_cast<const bf16x8*>(src + (n << 6) + ((cc ^ (n & 7)) << 3));
        *reinterpret_cast<bf16x8*>(Ai + (idx << 3)) = v;
      }
    }
    __syncthreads();
    // E phase: D[i,j]; wave w owns i-rows w*16..w*16+15
    const int irow_a = (w << 4) | m;
    bf16x8 a0 = *reinterpret_cast<const bf16x8*>(Ai + (irow_a << 6) + ((g ^ (irow_a & 7)) << 3));
    bf16x8 a1 = *reinterpret_cast<const bf16x8*>(Ai + (irow_a << 6) + (((g + 4) ^ (irow_a & 7)) << 3));
    f32x4 e[4];
#pragma unroll
    for (int n = 0; n < 4; ++n) {
      const int jrow = (n << 4) | m;
      bf16x8 b0v = *reinterpret_cast<const bf16x8*>(Bj + (jrow << 6) + ((g ^ (jrow & 7)) << 3));
      bf16x8 b1v = *reinterpret_cast<const bf16x8*>(Bj + (jrow << 6) + (((g + 4) ^ (jrow & 7)) << 3));
      e[n] = (f32x4){0.f, 0.f, 0.f, 0.f};
      e[n] = __builtin_amdgcn_mfma_f32_16x16x32_bf16(a0, b0v, e[n], 0, 0, 0);
      e[n] = __builtin_amdgcn_mfma_f32_16x16x32_bf16(a1, b1v, e[n], 0, 0, 0);
    }
    // exp + pack to Pl[j][i]; lane: j = n*16+m, i = w*16+g*4+r
    const int i = (w << 4) | (g << 2);
#pragma unroll
    for (int n = 0; n < 4; ++n) {
      const int jrow = (n << 4) | m;
      float p0 = __expf(-e[n][0]), p1 = __expf(-e[n][1]);
      float p2 = __expf(-e[n][2]), p3 = __expf(-e[n][3]);
      unsigned pk01 = (unsigned)f2bf(p0) | ((unsigned)f2bf(p1) << 16);
      unsigned pk23 = (unsigned)f2bf(p2) | ((unsigned)f2bf(p3) << 16);
      int base = jrow << 6;
      int off0 = base + ((((i) >> 3) ^ (jrow & 7)) << 3) + (i & 7);
      int off2 = base + ((((i + 2) >> 3) ^ (jrow & 7)) << 3) + ((i + 2) & 7);
      *reinterpret_cast<unsigned*>(Pl + off0) = pk01;
      *reinterpret_cast<unsigned*>(Pl + off2) = pk23;
    }
    // KA A-frags (global, [c][n] layout)
    const int crow = (w << 4) | m;
    const unsigned short* kap = KAc + nb + ((size_t)crow << 10) + i0 + (g << 3);
    bf16x8 ka0 = *reinterpret_cast<const bf16x8*>(kap);
    bf16x8 ka1 = *reinterpret_cast<const bf16x8*>(kap + 32);
    __syncthreads();
    // PtV: D[c,j] += KA(c,i) * P(i,j)
#pragma unroll
    for (int n = 0; n < 4; ++n) {
      const int jrow = (n << 4) | m;
      bf16x8 p0 = *reinterpret_cast<const bf16x8*>(Pl + (jrow << 6) + ((g ^ (jrow & 7)) << 3));
      bf16x8 p1 = *reinterpret_cast<const bf16x8*>(Pl + (jrow << 6) + (((g + 4) ^ (jrow & 7)) << 3));
      accO[n] = __builtin_amdgcn_mfma_f32_16x16x32_bf16(ka0, p0, accO[n], 0, 0, 0);
      accO[n] = __builtin_amdgcn_mfma_f32_16x16x32_bf16(ka1, p1, accO[n], 0, 0, 0);
    }
  }
  float* OUT = PART + ((size_t)blockIdx.y << 20) + ((size_t)(b * 64) << 10);
#pragma unroll
  for (int n = 0; n < 4; ++n) {
    const int jg = j0 + (n << 4) + m;
    const int c = (w << 4) + (g << 2);
#pragma unroll
    for (int r = 0; r < 4; ++r)
      OUT[((size_t)(c + r) << 10) + jg] = accO[n][r];
  }
}

// ---- sum 4 partials ---------------------------------------------------------
__global__ __launch_bounds__(256)
void part_reduce_kernel(const float* __restrict__ P, float* __restrict__ O) {
  const size_t i4 = ((size_t)blockIdx.x * 256 + threadIdx.x) << 2;
  float4 a = *reinterpret_cast<const float4*>(P + i4);
  float4 b = *reinterpret_cast<const float4*>(P + (1u << 20) + i4);
  float4 c = *reinterpret_cast<const float4*>(P + (2u << 20) + i4);
  float4 d = *reinterpret_cast<const float4*>(P + (3u << 20) + i4);
  float4 o;
  o.x = (a.x + b.x) + (c.x + d.x);
  o.y = (a.y + b.y) + (c.y + d.y);
  o.z = (a.z + b.z) + (c.z + d.z);
  o.w = (a.w + b.w) + (c.w + d.w);
  *reinterpret_cast<float4*>(O + i4) = o;
}

// ---------------- generalized conv1x1 (block phase, f32) --------------------
// MODE: 0 plain, 2 pre-BN-relu on input, 3 virtual-concat input
template<int CIN, int OG, int MODE, bool STATS>
__global__ __launch_bounds__(256)
void convg_kernel(const float* __restrict__ X0, const float* __restrict__ X1,
                  const float* __restrict__ W, const float* __restrict__ bias,
                  const float* __restrict__ prodSums, const float* __restrict__ gam,
                  const float* __restrict__ bet, const float* __restrict__ bsum,
                  float* __restrict__ Y, float* __restrict__ outSums, int Cout) {
  __shared__ float wsT[CIN][OG];
  __shared__ float scs[CIN];
  __shared__ float shs[CIN];
  __shared__ float sred[STATS ? 4 : 1][OG][2];
  constexpr int LOG = (OG == 4) ? 2 : 3;
  const int tid = threadIdx.x;
  const int o0 = blockIdx.x * OG;
  const int b  = blockIdx.z;
  const int px = (blockIdx.y << 9) + (tid << 1);

  float wscale1 = 1.f;
  if (MODE == 3) wscale1 = 1.f / bsum[b];
  for (int idx = tid; idx < CIN * OG; idx += 256) {
    int c = idx >> LOG, k = idx & (OG - 1);
    float w = W[(o0 + k) * CIN + c];
    if (MODE == 3 && c >= (CIN / 2)) w *= wscale1;
    wsT[c][k] = w;
  }
  if (MODE == 2) {
    const float invN = 1.f / 16384.f;
    for (int c = tid; c < CIN; c += 256) {
      float m  = prodSums[c] * invN;
      float vv = prodSums[256 + c] * invN - m * m;
      float sc = gam[c] * rsqrtf(vv + 1e-5f);
      scs[c] = sc;
      shs[c] = bet[c] - m * sc;
    }
  }
  __syncthreads();

  float acc[OG][2];
#pragma unroll
  for (int k = 0; k < OG; ++k) { acc[k][0] = 0.f; acc[k][1] = 0.f; }

  const float* xb0;
  const float* xb1 = nullptr;
  if (MODE == 3) {
    xb0 = X0 + (((size_t)b * 64) << 10);
    xb1 = X1 + (((size_t)b * 64) << 10);
  } else {
    xb0 = X0 + (((size_t)b * CIN) << 10);
  }

#pragma unroll 4
  for (int c = 0; c < CIN; ++c) {
    float2 xv;
    if (MODE == 3) {
      const float* src = (c < CIN / 2) ? (xb0 + (c << 10))
                                       : (xb1 + ((c - CIN / 2) << 10));
      xv = *reinterpret_cast<const float2*>(src + px);
    } else {
      xv = *reinterpret_cast<const float2*>(xb0 + (c << 10) + px);
    }
    if (MODE == 2) {
      xv.x = fmaxf(fmaf(xv.x, scs[c], shs[c]), 0.f);
      xv.y = fmaxf(fmaf(xv.y, scs[c], shs[c]), 0.f);
    }
    const float4* wrow = reinterpret_cast<const float4*>(wsT[c]);
    float4 wa = wrow[0];
    acc[0][0] = fmaf(wa.x, xv.x, acc[0][0]); acc[0][1] = fmaf(wa.x, xv.y, acc[0][1]);
    acc[1][0] = fmaf(wa.y, xv.x, acc[1][0]); acc[1][1] = fmaf(wa.y, xv.y, acc[1][1]);
    acc[2][0] = fmaf(wa.z, xv.x, acc[2][0]); acc[2][1] = fmaf(wa.z, xv.y, acc[2][1]);
    acc[3][0] = fmaf(wa.w, xv.x, acc[3][0]); acc[3][1] = fmaf(wa.w, xv.y, acc[3][1]);
    if (OG == 8) {
      float4 wb = wrow[1];
      acc[4][0] = fmaf(wb.x, xv.x, acc[4][0]); acc[4][1] = fmaf(wb.x, xv.y, acc[4][1]);
      acc[5][0] = fmaf(wb.y, xv.x, acc[5][0]); acc[5][1] = fmaf(wb.y, xv.y, acc[5][1]);
      acc[6][0] = fmaf(wb.z, xv.x, acc[6][0]); acc[6][1] = fmaf(wb.z, xv.y, acc[6][1]);
      acc[7][0] = fmaf(wb.w, xv.x, acc[7][0]); acc[7][1] = fmaf(wb.w, xv.y, acc[7][1]);
    }
  }

#pragma unroll
  for (int k = 0; k < OG; ++k) {
    float2 o;
    o.x = acc[k][0]; o.y = acc[k][1];
    *reinterpret_cast<float2*>(Y + (((size_t)(b * Cout + o0 + k)) << 10) + px) = o;
  }

  if (STATS) {
    const int lane = tid & 63, wv = tid >> 6;
#pragma unroll
    for (int k = 0; k < OG; ++k) {
      float s = acc[k][0] + acc[k][1];
      float q = acc[k][0] * acc[k][0] + acc[k][1] * acc[k][1];
      for (int off = 32; off; off >>= 1) {
        s += __shfl_down(s, off);
        q += __shfl_down(q, off);
      }
      if (lane == 0) { sred[wv][k][0] = s; sred[wv][k][1] = q; }
    }
    __syncthreads();
    if (tid < OG) {
      float s = sred[0][tid][0] + sred[1][tid][0] + sred[2][tid][0] + sred[3][tid][0];
      float q = sred[0][tid][1] + sred[1][tid][1] + sred[2][tid][1] + sred[3][tid][1];
      atomicAdd(&outSums[o0 + tid], s);
      atomicAdd(&outSums[256 + o0 + tid], q);
    }
  }
}

// ---------------- O = relu(bn(T) + concat-residual) -------------------------
__global__ __launch_bounds__(256)
void epil_add_kernel(const float* __restrict__ T, const float* __restrict__ sums,
                     const float* __restrict__ gam, const float* __restrict__ bet,
                     const float* __restrict__ XR, const float* __restrict__ ATT,
                     const float* __restrict__ bsum, float* __restrict__ O) {
  const int i4 = (blockIdx.x * 256 + threadIdx.x) << 2;
  const int c = (i4 >> 10) & 127;
  const int b = i4 >> 17;
  const int n = i4 & 1023;
  const float invN = 1.f / 16384.f;
  float m  = sums[c] * invN;
  float vv = sums[256 + c] * invN - m * m;
  float sc = gam[c] * rsqrtf(vv + 1e-5f);
  float sh = bet[c] - m * sc;
  float4 t = *reinterpret_cast<const float4*>(T + i4);
  float4 r;
  if (c < 64) {
    r = *reinterpret_cast<const float4*>(XR + (((size_t)(b * 64 + c)) << 10) + n);
  } else {
    r = *reinterpret_cast<const float4*>(ATT + (((size_t)(b * 64 + c - 64)) << 10) + n);
    float inv = 1.f / bsum[b];
    r.x *= inv; r.y *= inv; r.z *= inv; r.w *= inv;
  }
  float4 o;
  o.x = fmaxf(fmaf(t.x, sc, sh) + r.x, 0.f);
  o.y = fmaxf(fmaf(t.y, sc, sh) + r.y, 0.f);
  o.z = fmaxf(fmaf(t.z, sc, sh) + r.z, 0.f);
  o.w = fmaxf(fmaf(t.w, sc, sh) + r.w, 0.f);
  *reinterpret_cast<float4*>(O + i4) = o;
}

// ---------------- O = relu(bn0(T) + bn1(S)) ---------------------------------
__global__ __launch_bounds__(256)
void epil2_kernel(const float* __restrict__ T, const float* __restrict__ sums0,
                  const float* __restrict__ g0, const float* __restrict__ b0,
                  const float* __restrict__ S, const float* __restrict__ sums1,
                  const float* __restrict__ g1, const float* __restrict__ b1,
                  float* __restrict__ O) {
  const int i4 = (blockIdx.x * 256 + threadIdx.x) << 2;
  const int c = (i4 >> 10) & 255;
  const float invN = 1.f / 16384.f;
  float m0 = sums0[c] * invN;
  float v0 = sums0[256 + c] * invN - m0 * m0;
  float a0 = g0[c] * rsqrtf(v0 + 1e-5f);
  float h0 = b0[c] - m0 * a0;
  float m1 = sums1[c] * invN;
  float v1 = sums1[256 + c] * invN - m1 * m1;
  float a1 = g1[c] * rsqrtf(v1 + 1e-5f);
  float h1 = b1[c] - m1 * a1;
  float4 t = *reinterpret_cast<const float4*>(T + i4);
  float4 s = *reinterpret_cast<const float4*>(S + i4);
  float4 o;
  o.x = fmaxf(fmaf(t.x, a0, h0) + fmaf(s.x, a1, h1), 0.f);
  o.y = fmaxf(fmaf(t.y, a0, h0) + fmaf(s.y, a1, h1), 0.f);
  o.z = fmaxf(fmaf(t.z, a0, h0) + fmaf(s.z, a1, h1), 0.f);
  o.w = fmaxf(fmaf(t.w, a0, h0) + fmaf(s.w, a1, h1), 0.f);
  *reinterpret_cast<float4*>(O + i4) = o;
}

// ---------------- final: out = bn(F) as f32 ---------------------------------
__global__ __launch_bounds__(256)
void writeout_kernel(const float* __restrict__ F, const float* __restrict__ sums,
                     const float* __restrict__ gam, const float* __restrict__ bet,
                     float* __restrict__ out) {
  const int i4 = (blockIdx.x * 256 + threadIdx.x) << 2;
  const int c = (i4 >> 10) & 63;
  const float invN = 1.f / 16384.f;
  float m  = sums[c] * invN;
  float vv = sums[256 + c] * invN - m * m;
  float sc = gam[c] * rsqrtf(vv + 1e-5f);
  float sh = bet[c] - m * sc;
  float4 v = *reinterpret_cast<const float4*>(F + i4);
  float4 o;
  o.x = fmaf(v.x, sc, sh); o.y = fmaf(v.y, sc, sh);
  o.z = fmaf(v.z, sc, sh); o.w = fmaf(v.w, sc, sh);
  *reinterpret_cast<float4*>(out + i4) = o;
}

// ============================ host side =====================================
extern "C" void kernel_launch(void* const* d_in, const int* in_sizes, int n_in,
                              void* d_out, int out_size, void* d_ws, size_t ws_size,
                              hipStream_t stream) {
  float* wsf = (float*)d_ws;
  const size_t M1 = (size_t)1 << 20;
  const size_t H1 = (size_t)1 << 19;

  float* PAR = wsf;                    // 0.5M params
  float* XAF = wsf + H1;               // 1M
  float* XBF = wsf + H1 + 1 * M1;      // 1M
  float* R0  = wsf + H1 + 2 * M1;      // 4M (first 2M: bf16 Q/K buffers)
  float* R1  = wsf + H1 + 6 * M1;      // 4M
  float* XBA = wsf + H1 + 10 * M1;     // 1M
  float* XAA = wsf + H1 + 11 * M1;     // 1M
  float* R2  = wsf + H1 + 12 * M1;     // 4M (PART, then SC)
  float* O1  = wsf + H1 + 16 * M1;     // 2M
  float* tail = wsf + H1 + 18 * M1;
  float* bsum  = tail;                 // 16
  float* stats = tail + 16;            // 12 * 512
  int*   flag  = (int*)(tail + 16 + 12 * 512);

  unsigned short* QAt = (unsigned short*)R0;              // [b][n][c] bf16, 1M shorts
  unsigned short* QBt = (unsigned short*)(R0 + H1);       // 0.5M f32 = 1M shorts each
  unsigned short* KAc = (unsigned short*)(R0 + 2 * H1);   // [b][c][n] bf16
  unsigned short* KBc = (unsigned short*)(R0 + 3 * H1);

  // ---- import all inputs to f32 ----
  ImportArgs ia;
  const float* pp[46];
  ia.p[0] = d_in[0]; ia.sz[0] = in_sizes[0]; ia.off[0] = (int)(H1);
  ia.p[1] = d_in[1]; ia.sz[1] = in_sizes[1]; ia.off[1] = (int)(H1 + M1);
  pp[0] = XAF; pp[1] = XBF;
  int run = 0;
  for (int i = 2; i < 46 && i < n_in; ++i) {
    ia.p[i] = d_in[i]; ia.sz[i] = in_sizes[i]; ia.off[i] = run;
    pp[i] = PAR + run;
    run += in_sizes[i];
  }

  detect_kernel<<<1, 256, 0, stream>>>((const unsigned*)d_in[0], flag);
  import_kernel<<<dim3(46, 16), 256, 0, stream>>>(ia, wsf, flag);
  init_kernel<<<1, 256, 0, stream>>>(tail, 16 + 12 * 512);

  float* ST[12];
  for (int i = 0; i < 12; ++i) ST[i] = stats + i * 512;

  // ---- q/k convs -> bf16 dual layouts ----
  dim3 gq(16, 2, BATCH);
  conv_qk_kernel<0><<<gq, 256, 0, stream>>>(XAF, pp[2], pp[3], QAt);
  conv_qk_kernel<0><<<gq, 256, 0, stream>>>(XBF, pp[4], pp[5], QBt);
  conv_qk_kernel<1><<<gq, 256, 0, stream>>>(XAF, pp[6], pp[7], KAc);
  conv_qk_kernel<1><<<gq, 256, 0, stream>>>(XBF, pp[8], pp[9], KBc);

  // ---- MFMA attention (4-way split partials in R2) ----
  pv_mfma_kernel<<<dim3(16, 4, BATCH), 256, 0, stream>>>(QAt, QBt, KBc, R2, bsum);
  part_reduce_kernel<<<1024, 256, 0, stream>>>(R2, XBA);
  tpv_mfma_kernel<<<dim3(16, 4, BATCH), 256, 0, stream>>>(QAt, QBt, KAc, R2);
  part_reduce_kernel<<<1024, 256, 0, stream>>>(R2, XAA);

  for (int sbi = 0; sbi < 2; ++sbi) {
    const float* XR  = sbi ? XBF : XAF;
    const float* ATT = sbi ? XAA : XBA;
    const int base1 = sbi ? 16 : 10;
    const int base2 = sbi ? 31 : 22;
    const int baseo = sbi ? 43 : 40;
    float* s_t1a = ST[sbi * 6 + 0];
    float* s_t2a = ST[sbi * 6 + 1];
    float* s_t1b = ST[sbi * 6 + 2];
    float* s_t2b = ST[sbi * 6 + 3];
    float* s_sc  = ST[sbi * 6 + 4];
    float* s_o   = ST[sbi * 6 + 5];

    // ---- block 1 (128 -> 128) ----
    convg_kernel<128, 8, 3, true><<<dim3(16, 2, BATCH), 256, 0, stream>>>(
        XR, ATT, pp[base1 + 0], nullptr, nullptr, nullptr, nullptr, bsum, R0, s_t1a, 128);
    convg_kernel<128, 8, 2, true><<<dim3(16, 2, BATCH), 256, 0, stream>>>(
        R0, nullptr, pp[base1 + 3], nullptr, s_t1a, pp[base1 + 1], pp[base1 + 2], nullptr,
        R1, s_t2a, 128);
    epil_add_kernel<<<BATCH * 128, 256, 0, stream>>>(
        R1, s_t2a, pp[base1 + 4], pp[base1 + 5], XR, ATT, bsum, O1);

    // ---- block 2 (128 -> 256, with shortcut) ----
    convg_kernel<128, 8, 0, true><<<dim3(32, 2, BATCH), 256, 0, stream>>>(
        O1, nullptr, pp[base2 + 0], nullptr, nullptr, nullptr, nullptr, nullptr,
        R0, s_t1b, 256);
    convg_kernel<256, 8, 2, true><<<dim3(32, 2, BATCH), 256, 0, stream>>>(
        R0, nullptr, pp[base2 + 3], nullptr, s_t1b, pp[base2 + 1], pp[base2 + 2], nullptr,
        R1, s_t2b, 256);
    convg_kernel<128, 8, 0, true><<<dim3(32, 2, BATCH), 256, 0, stream>>>(
        O1, nullptr, pp[base2 + 6], nullptr, nullptr, nullptr, nullptr, nullptr,
        R2, s_sc, 256);
    epil2_kernel<<<BATCH * 256, 256, 0, stream>>>(
        R1, s_t2b, pp[base2 + 4], pp[base2 + 5], R2, s_sc, pp[base2 + 7], pp[base2 + 8], R0);

    // ---- output conv (256 -> 64) + BN ----
    convg_kernel<256, 4, 0, true><<<dim3(16, 2, BATCH), 256, 0, stream>>>(
        R0, nullptr, pp[baseo + 0], nullptr, nullptr, nullptr, nullptr, nullptr,
        R1, s_o, 64);
    writeout_kernel<<<1024, 256, 0, stream>>>(
        R1, s_o, pp[baseo + 1], pp[baseo + 2], (float*)d_out + sbi * M1);
  }
}

// Round 6
// 478.428 us; speedup vs baseline: 2.1628x; 1.1426x over previous
//
#include <hip/hip_runtime.h>
#include <hip/hip_bf16.h>
#include <cstddef>

static constexpr int BATCH = 16;   // B
static constexpr int NPIX  = 1024; // H*W

typedef __attribute__((ext_vector_type(8))) short bf16x8;
typedef __attribute__((ext_vector_type(4))) float f32x4;

__device__ __forceinline__ unsigned short f2bf(float f) {
  unsigned u = __float_as_uint(f);
  unsigned r = (u + 0x7fffu + ((u >> 16) & 1u)) >> 16;  // RNE
  return (unsigned short)r;
}

__global__ void init_kernel(float* __restrict__ tail, int n) {
  for (int i = threadIdx.x; i < n; i += 256) tail[i] = 0.f;
}

// ---------------- q/k conv: f32 [b][c][n] -> bf16, dual layouts -------------
// TR=0: Yt[b][n][64c]  (Q operands).  TR=1: Yc[b][c][n]  (K operands).
template<int TR>
__global__ __launch_bounds__(256)
void conv_qk_kernel(const float* __restrict__ X, const float* __restrict__ W,
                    const float* __restrict__ bias, unsigned short* __restrict__ Y) {
  __shared__ float wsT[64][4];
  const int tid = threadIdx.x;
  const int o0 = blockIdx.x << 2;
  const int b  = blockIdx.z;
  const int px = (blockIdx.y << 9) + (tid << 1);
  {
    int c = tid >> 2, k = tid & 3;
    wsT[c][k] = W[((o0 + k) << 6) + c];
  }
  __syncthreads();
  float acc[4][2] = {};
  const float* xb = X + ((size_t)b << 16) + px;
#pragma unroll 4
  for (int c = 0; c < 64; ++c) {
    float2 xv = *reinterpret_cast<const float2*>(xb + (c << 10));
    float4 w = *reinterpret_cast<const float4*>(wsT[c]);
    acc[0][0] = fmaf(w.x, xv.x, acc[0][0]); acc[0][1] = fmaf(w.x, xv.y, acc[0][1]);
    acc[1][0] = fmaf(w.y, xv.x, acc[1][0]); acc[1][1] = fmaf(w.y, xv.y, acc[1][1]);
    acc[2][0] = fmaf(w.z, xv.x, acc[2][0]); acc[2][1] = fmaf(w.z, xv.y, acc[2][1]);
    acc[3][0] = fmaf(w.w, xv.x, acc[3][0]); acc[3][1] = fmaf(w.w, xv.y, acc[3][1]);
  }
  float b0 = bias[o0], b1 = bias[o0 + 1], b2 = bias[o0 + 2], b3 = bias[o0 + 3];
  if (TR == 0) {
    ushort4 v0, v1;
    v0.x = f2bf(acc[0][0] + b0); v0.y = f2bf(acc[1][0] + b1);
    v0.z = f2bf(acc[2][0] + b2); v0.w = f2bf(acc[3][0] + b3);
    v1.x = f2bf(acc[0][1] + b0); v1.y = f2bf(acc[1][1] + b1);
    v1.z = f2bf(acc[2][1] + b2); v1.w = f2bf(acc[3][1] + b3);
    unsigned short* yt = Y + ((size_t)b << 16) + ((size_t)px << 6) + o0;
    *reinterpret_cast<ushort4*>(yt) = v0;
    *reinterpret_cast<ushort4*>(yt + 64) = v1;
  } else {
    float bv[4] = {b0, b1, b2, b3};
#pragma unroll
    for (int k = 0; k < 4; ++k) {
      ushort2 v;
      v.x = f2bf(acc[k][0] + bv[k]); v.y = f2bf(acc[k][1] + bv[k]);
      *reinterpret_cast<ushort2*>(Y + ((size_t)b << 16) + ((size_t)(o0 + k) << 10) + px) = v;
    }
  }
}

// ---- MFMA fused PV: PART[jc][b,c,i] = sum_{j in chunk} exp(-E[i,j]) KB[c,j] -
__global__ __launch_bounds__(256)
void pv_mfma_kernel(const unsigned short* __restrict__ QAt,
                    const unsigned short* __restrict__ QBt,
                    const unsigned short* __restrict__ KBc,
                    float* __restrict__ PART, float* __restrict__ bsum) {
  __shared__ __align__(16) unsigned short Ai[4096];  // QA tile [i][c] swz
  __shared__ __align__(16) unsigned short Bj[4096];  // QB tile [j][c] swz
  __shared__ __align__(16) unsigned short Pl[4096];  // P tile [i][j] swz
  __shared__ float red[256];
  const int tid = threadIdx.x;
  const int lane = tid & 63, w = tid >> 6;
  const int g = lane >> 4, m = lane & 15;
  const int i0 = blockIdx.x << 6;
  const int jbase = blockIdx.y << 8;
  const int b = blockIdx.z;
  const size_t nb = (size_t)b << 16;

  {
    const unsigned short* src = QAt + nb + ((size_t)i0 << 6);
#pragma unroll
    for (int s = 0; s < 2; ++s) {
      int idx = tid + (s << 8);
      int n = idx >> 3, cc = idx & 7;
      bf16x8 v = *reinterpret_cast<const bf16x8*>(src + (n << 6) + ((cc ^ (n & 7)) << 3));
      *reinterpret_cast<bf16x8*>(Ai + (idx << 3)) = v;
    }
  }
  f32x4 accO[4];
#pragma unroll
  for (int n = 0; n < 4; ++n) accO[n] = (f32x4){0.f, 0.f, 0.f, 0.f};
  float psum = 0.f;

  for (int jt = 0; jt < 4; ++jt) {
    const int j0 = jbase + (jt << 6);
    __syncthreads();
    {
      const unsigned short* src = QBt + nb + ((size_t)j0 << 6);
#pragma unroll
      for (int s = 0; s < 2; ++s) {
        int idx = tid + (s << 8);
        int n = idx >> 3, cc = idx & 7;
        bf16x8 v = *reinterpret_cast<const bf16x8*>(src + (n << 6) + ((cc ^ (n & 7)) << 3));
        *reinterpret_cast<bf16x8*>(Bj + (idx << 3)) = v;
      }
    }
    __syncthreads();
    const int jrow = (w << 4) | m;
    bf16x8 a0 = *reinterpret_cast<const bf16x8*>(Bj + (jrow << 6) + ((g ^ (jrow & 7)) << 3));
    bf16x8 a1 = *reinterpret_cast<const bf16x8*>(Bj + (jrow << 6) + (((g + 4) ^ (jrow & 7)) << 3));
    f32x4 e[4];
#pragma unroll
    for (int n = 0; n < 4; ++n) {
      const int irow = (n << 4) | m;
      bf16x8 b0v = *reinterpret_cast<const bf16x8*>(Ai + (irow << 6) + ((g ^ (irow & 7)) << 3));
      bf16x8 b1v = *reinterpret_cast<const bf16x8*>(Ai + (irow << 6) + (((g + 4) ^ (irow & 7)) << 3));
      e[n] = (f32x4){0.f, 0.f, 0.f, 0.f};
      e[n] = __builtin_amdgcn_mfma_f32_16x16x32_bf16(a0, b0v, e[n], 0, 0, 0);
      e[n] = __builtin_amdgcn_mfma_f32_16x16x32_bf16(a1, b1v, e[n], 0, 0, 0);
    }
    const int j = (w << 4) | (g << 2);
#pragma unroll
    for (int n = 0; n < 4; ++n) {
      const int irow = (n << 4) | m;
      float p0 = __expf(-e[n][0]), p1 = __expf(-e[n][1]);
      float p2 = __expf(-e[n][2]), p3 = __expf(-e[n][3]);
      psum += (p0 + p1) + (p2 + p3);
      unsigned pk01 = (unsigned)f2bf(p0) | ((unsigned)f2bf(p1) << 16);
      unsigned pk23 = (unsigned)f2bf(p2) | ((unsigned)f2bf(p3) << 16);
      int base = irow << 6;
      int off0 = base + ((((j) >> 3) ^ (irow & 7)) << 3) + (j & 7);
      int off2 = base + ((((j + 2) >> 3) ^ (irow & 7)) << 3) + ((j + 2) & 7);
      *reinterpret_cast<unsigned*>(Pl + off0) = pk01;
      *reinterpret_cast<unsigned*>(Pl + off2) = pk23;
    }
    const int crow = (w << 4) | m;
    const unsigned short* kbp = KBc + nb + ((size_t)crow << 10) + j0 + (g << 3);
    bf16x8 ka0 = *reinterpret_cast<const bf16x8*>(kbp);
    bf16x8 ka1 = *reinterpret_cast<const bf16x8*>(kbp + 32);
    __syncthreads();
#pragma unroll
    for (int n = 0; n < 4; ++n) {
      const int irow = (n << 4) | m;
      bf16x8 p0 = *reinterpret_cast<const bf16x8*>(Pl + (irow << 6) + ((g ^ (irow & 7)) << 3));
      bf16x8 p1 = *reinterpret_cast<const bf16x8*>(Pl + (irow << 6) + (((g + 4) ^ (irow & 7)) << 3));
      accO[n] = __builtin_amdgcn_mfma_f32_16x16x32_bf16(ka0, p0, accO[n], 0, 0, 0);
      accO[n] = __builtin_amdgcn_mfma_f32_16x16x32_bf16(ka1, p1, accO[n], 0, 0, 0);
    }
  }
  float* OUT = PART + ((size_t)blockIdx.y << 20) + ((size_t)(b * 64) << 10);
#pragma unroll
  for (int n = 0; n < 4; ++n) {
    const int ig = i0 + (n << 4) + m;
    const int c = (w << 4) + (g << 2);
#pragma unroll
    for (int r = 0; r < 4; ++r)
      OUT[((size_t)(c + r) << 10) + ig] = accO[n][r];
  }
  red[tid] = psum; __syncthreads();
  for (int s = 128; s > 0; s >>= 1) {
    if (tid < s) red[tid] += red[tid + s];
    __syncthreads();
  }
  if (tid == 0) atomicAdd(bsum + b, red[0]);
}

// ---- MFMA fused PtV: PART[ic][b,c,j] = sum_{i in chunk} exp(-E[i,j]) KA[c,i]
__global__ __launch_bounds__(256)
void tpv_mfma_kernel(const unsigned short* __restrict__ QAt,
                     const unsigned short* __restrict__ QBt,
                     const unsigned short* __restrict__ KAc,
                     float* __restrict__ PART) {
  __shared__ __align__(16) unsigned short Bj[4096];
  __shared__ __align__(16) unsigned short Ai[4096];
  __shared__ __align__(16) unsigned short Pl[4096];
  const int tid = threadIdx.x;
  const int lane = tid & 63, w = tid >> 6;
  const int g = lane >> 4, m = lane & 15;
  const int j0 = blockIdx.x << 6;
  const int ibase = blockIdx.y << 8;
  const int b = blockIdx.z;
  const size_t nb = (size_t)b << 16;

  {
    const unsigned short* src = QBt + nb + ((size_t)j0 << 6);
#pragma unroll
    for (int s = 0; s < 2; ++s) {
      int idx = tid + (s << 8);
      int n = idx >> 3, cc = idx & 7;
      bf16x8 v = *reinterpret_cast<const bf16x8*>(src + (n << 6) + ((cc ^ (n & 7)) << 3));
      *reinterpret_cast<bf16x8*>(Bj + (idx << 3)) = v;
    }
  }
  f32x4 accO[4];
#pragma unroll
  for (int n = 0; n < 4; ++n) accO[n] = (f32x4){0.f, 0.f, 0.f, 0.f};

  for (int it = 0; it < 4; ++it) {
    const int i0 = ibase + (it << 6);
    __syncthreads();
    {
      const unsigned short* src = QAt + nb + ((size_t)i0 << 6);
#pragma unroll
      for (int s = 0; s < 2; ++s) {
        int idx = tid + (s << 8);
        int n = idx >> 3, cc = idx & 7;
        bf16x8 v = *reinterpret_cast<const bf16x8*>(src + (n << 6) + ((cc ^ (n & 7)) << 3));
        *reinterpret_cast<bf16x8*>(Ai + (idx << 3)) = v;
      }
    }
    __syncthreads();
    const int irow_a = (w << 4) | m;
    bf16x8 a0 = *reinterpret_cast<const bf16x8*>(Ai + (irow_a << 6) + ((g ^ (irow_a & 7)) << 3));
    bf16x8 a1 = *reinterpret_cast<const bf16x8*>(Ai + (irow_a << 6) + (((g + 4) ^ (irow_a & 7)) << 3));
    f32x4 e[4];
#pragma unroll
    for (int n = 0; n < 4; ++n) {
      const int jrow = (n << 4) | m;
      bf16x8 b0v = *reinterpret_cast<const bf16x8*>(Bj + (jrow << 6) + ((g ^ (jrow & 7)) << 3));
      bf16x8 b1v = *reinterpret_cast<const bf16x8*>(Bj + (jrow << 6) + (((g + 4) ^ (jrow & 7)) << 3));
      e[n] = (f32x4){0.f, 0.f, 0.f, 0.f};
      e[n] = __builtin_amdgcn_mfma_f32_16x16x32_bf16(a0, b0v, e[n], 0, 0, 0);
      e[n] = __builtin_amdgcn_mfma_f32_16x16x32_bf16(a1, b1v, e[n], 0, 0, 0);
    }
    const int i = (w << 4) | (g << 2);
#pragma unroll
    for (int n = 0; n < 4; ++n) {
      const int jrow = (n << 4) | m;
      float p0 = __expf(-e[n][0]), p1 = __expf(-e[n][1]);
      float p2 = __expf(-e[n][2]), p3 = __expf(-e[n][3]);
      unsigned pk01 = (unsigned)f2bf(p0) | ((unsigned)f2bf(p1) << 16);
      unsigned pk23 = (unsigned)f2bf(p2) | ((unsigned)f2bf(p3) << 16);
      int base = jrow << 6;
      int off0 = base + ((((i) >> 3) ^ (jrow & 7)) << 3) + (i & 7);
      int off2 = base + ((((i + 2) >> 3) ^ (jrow & 7)) << 3) + ((i + 2) & 7);
      *reinterpret_cast<unsigned*>(Pl + off0) = pk01;
      *reinterpret_cast<unsigned*>(Pl + off2) = pk23;
    }
    const int crow = (w << 4) | m;
    const unsigned short* kap = KAc + nb + ((size_t)crow << 10) + i0 + (g << 3);
    bf16x8 ka0 = *reinterpret_cast<const bf16x8*>(kap);
    bf16x8 ka1 = *reinterpret_cast<const bf16x8*>(kap + 32);
    __syncthreads();
#pragma unroll
    for (int n = 0; n < 4; ++n) {
      const int jrow = (n << 4) | m;
      bf16x8 p0 = *reinterpret_cast<const bf16x8*>(Pl + (jrow << 6) + ((g ^ (jrow & 7)) << 3));
      bf16x8 p1 = *reinterpret_cast<const bf16x8*>(Pl + (jrow << 6) + (((g + 4) ^ (jrow & 7)) << 3));
      accO[n] = __builtin_amdgcn_mfma_f32_16x16x32_bf16(ka0, p0, accO[n], 0, 0, 0);
      accO[n] = __builtin_amdgcn_mfma_f32_16x16x32_bf16(ka1, p1, accO[n], 0, 0, 0);
    }
  }
  float* OUT = PART + ((size_t)blockIdx.y << 20) + ((size_t)(b * 64) << 10);
#pragma unroll
  for (int n = 0; n < 4; ++n) {
    const int jg = j0 + (n << 4) + m;
    const int c = (w << 4) + (g << 2);
#pragma unroll
    for (int r = 0; r < 4; ++r)
      OUT[((size_t)(c + r) << 10) + jg] = accO[n][r];
  }
}

// ---- sum 4 partials ---------------------------------------------------------
__global__ __launch_bounds__(256)
void part_reduce_kernel(const float* __restrict__ P, float* __restrict__ O) {
  const size_t i4 = ((size_t)blockIdx.x * 256 + threadIdx.x) << 2;
  float4 a = *reinterpret_cast<const float4*>(P + i4);
  float4 b = *reinterpret_cast<const float4*>(P + (1u << 20) + i4);
  float4 c = *reinterpret_cast<const float4*>(P + (2u << 20) + i4);
  float4 d = *reinterpret_cast<const float4*>(P + (3u << 20) + i4);
  float4 o;
  o.x = (a.x + b.x) + (c.x + d.x);
  o.y = (a.y + b.y) + (c.y + d.y);
  o.z = (a.z + b.z) + (c.z + d.z);
  o.w = (a.w + b.w) + (c.w + d.w);
  *reinterpret_cast<float4*>(O + i4) = o;
}

// ---------------- generalized conv1x1 (block phase, f32) --------------------
// MODE: 0 plain, 2 pre-BN-relu on input, 3 virtual-concat input
template<int CIN, int OG, int MODE, bool STATS>
__global__ __launch_bounds__(256)
void convg_kernel(const float* __restrict__ X0, const float* __restrict__ X1,
                  const float* __restrict__ W, const float* __restrict__ bias,
                  const float* __restrict__ prodSums, const float* __restrict__ gam,
                  const float* __restrict__ bet, const float* __restrict__ bsum,
                  float* __restrict__ Y, float* __restrict__ outSums, int Cout) {
  __shared__ float wsT[CIN][OG];
  __shared__ float scs[CIN];
  __shared__ float shs[CIN];
  __shared__ float sred[STATS ? 4 : 1][OG][2];
  constexpr int LOG = (OG == 4) ? 2 : 3;
  const int tid = threadIdx.x;
  const int o0 = blockIdx.x * OG;
  const int b  = blockIdx.z;
  const int px = (blockIdx.y << 9) + (tid << 1);

  float wscale1 = 1.f;
  if (MODE == 3) wscale1 = 1.f / bsum[b];
  for (int idx = tid; idx < CIN * OG; idx += 256) {
    int c = idx >> LOG, k = idx & (OG - 1);
    float w = W[(o0 + k) * CIN + c];
    if (MODE == 3 && c >= (CIN / 2)) w *= wscale1;
    wsT[c][k] = w;
  }
  if (MODE == 2) {
    const float invN = 1.f / 16384.f;
    for (int c = tid; c < CIN; c += 256) {
      float m  = prodSums[c] * invN;
      float vv = prodSums[256 + c] * invN - m * m;
      float sc = gam[c] * rsqrtf(vv + 1e-5f);
      scs[c] = sc;
      shs[c] = bet[c] - m * sc;
    }
  }
  __syncthreads();

  float acc[OG][2];
#pragma unroll
  for (int k = 0; k < OG; ++k) { acc[k][0] = 0.f; acc[k][1] = 0.f; }

  const float* xb0;
  const float* xb1 = nullptr;
  if (MODE == 3) {
    xb0 = X0 + (((size_t)b * 64) << 10);
    xb1 = X1 + (((size_t)b * 64) << 10);
  } else {
    xb0 = X0 + (((size_t)b * CIN) << 10);
  }

#pragma unroll 4
  for (int c = 0; c < CIN; ++c) {
    float2 xv;
    if (MODE == 3) {
      const float* src = (c < CIN / 2) ? (xb0 + (c << 10))
                                       : (xb1 + ((c - CIN / 2) << 10));
      xv = *reinterpret_cast<const float2*>(src + px);
    } else {
      xv = *reinterpret_cast<const float2*>(xb0 + (c << 10) + px);
    }
    if (MODE == 2) {
      xv.x = fmaxf(fmaf(xv.x, scs[c], shs[c]), 0.f);
      xv.y = fmaxf(fmaf(xv.y, scs[c], shs[c]), 0.f);
    }
    const float4* wrow = reinterpret_cast<const float4*>(wsT[c]);
    float4 wa = wrow[0];
    acc[0][0] = fmaf(wa.x, xv.x, acc[0][0]); acc[0][1] = fmaf(wa.x, xv.y, acc[0][1]);
    acc[1][0] = fmaf(wa.y, xv.x, acc[1][0]); acc[1][1] = fmaf(wa.y, xv.y, acc[1][1]);
    acc[2][0] = fmaf(wa.z, xv.x, acc[2][0]); acc[2][1] = fmaf(wa.z, xv.y, acc[2][1]);
    acc[3][0] = fmaf(wa.w, xv.x, acc[3][0]); acc[3][1] = fmaf(wa.w, xv.y, acc[3][1]);
    if (OG == 8) {
      float4 wb = wrow[1];
      acc[4][0] = fmaf(wb.x, xv.x, acc[4][0]); acc[4][1] = fmaf(wb.x, xv.y, acc[4][1]);
      acc[5][0] = fmaf(wb.y, xv.x, acc[5][0]); acc[5][1] = fmaf(wb.y, xv.y, acc[5][1]);
      acc[6][0] = fmaf(wb.z, xv.x, acc[6][0]); acc[6][1] = fmaf(wb.z, xv.y, acc[6][1]);
      acc[7][0] = fmaf(wb.w, xv.x, acc[7][0]); acc[7][1] = fmaf(wb.w, xv.y, acc[7][1]);
    }
  }

#pragma unroll
  for (int k = 0; k < OG; ++k) {
    float2 o;
    o.x = acc[k][0]; o.y = acc[k][1];
    *reinterpret_cast<float2*>(Y + (((size_t)(b * Cout + o0 + k)) << 10) + px) = o;
  }

  if (STATS) {
    const int lane = tid & 63, wv = tid >> 6;
#pragma unroll
    for (int k = 0; k < OG; ++k) {
      float s = acc[k][0] + acc[k][1];
      float q = acc[k][0] * acc[k][0] + acc[k][1] * acc[k][1];
      for (int off = 32; off; off >>= 1) {
        s += __shfl_down(s, off);
        q += __shfl_down(q, off);
      }
      if (lane == 0) { sred[wv][k][0] = s; sred[wv][k][1] = q; }
    }
    __syncthreads();
    if (tid < OG) {
      float s = sred[0][tid][0] + sred[1][tid][0] + sred[2][tid][0] + sred[3][tid][0];
      float q = sred[0][tid][1] + sred[1][tid][1] + sred[2][tid][1] + sred[3][tid][1];
      atomicAdd(&outSums[o0 + tid], s);
      atomicAdd(&outSums[256 + o0 + tid], q);
    }
  }
}

// ---------------- O = relu(bn(T) + concat-residual) -------------------------
__global__ __launch_bounds__(256)
void epil_add_kernel(const float* __restrict__ T, const float* __restrict__ sums,
                     const float* __restrict__ gam, const float* __restrict__ bet,
                     const float* __restrict__ XR, const float* __restrict__ ATT,
                     const float* __restrict__ bsum, float* __restrict__ O) {
  const int i4 = (blockIdx.x * 256 + threadIdx.x) << 2;
  const int c = (i4 >> 10) & 127;
  const int b = i4 >> 17;
  const int n = i4 & 1023;
  const float invN = 1.f / 16384.f;
  float m  = sums[c] * invN;
  float vv = sums[256 + c] * invN - m * m;
  float sc = gam[c] * rsqrtf(vv + 1e-5f);
  float sh = bet[c] - m * sc;
  float4 t = *reinterpret_cast<const float4*>(T + i4);
  float4 r;
  if (c < 64) {
    r = *reinterpret_cast<const float4*>(XR + (((size_t)(b * 64 + c)) << 10) + n);
  } else {
    r = *reinterpret_cast<const float4*>(ATT + (((size_t)(b * 64 + c - 64)) << 10) + n);
    float inv = 1.f / bsum[b];
    r.x *= inv; r.y *= inv; r.z *= inv; r.w *= inv;
  }
  float4 o;
  o.x = fmaxf(fmaf(t.x, sc, sh) + r.x, 0.f);
  o.y = fmaxf(fmaf(t.y, sc, sh) + r.y, 0.f);
  o.z = fmaxf(fmaf(t.z, sc, sh) + r.z, 0.f);
  o.w = fmaxf(fmaf(t.w, sc, sh) + r.w, 0.f);
  *reinterpret_cast<float4*>(O + i4) = o;
}

// ---------------- O = relu(bn0(T) + bn1(S)) ---------------------------------
__global__ __launch_bounds__(256)
void epil2_kernel(const float* __restrict__ T, const float* __restrict__ sums0,
                  const float* __restrict__ g0, const float* __restrict__ b0,
                  const float* __restrict__ S, const float* __restrict__ sums1,
                  const float* __restrict__ g1, const float* __restrict__ b1,
                  float* __restrict__ O) {
  const int i4 = (blockIdx.x * 256 + threadIdx.x) << 2;
  const int c = (i4 >> 10) & 255;
  const float invN = 1.f / 16384.f;
  float m0 = sums0[c] * invN;
  float v0 = sums0[256 + c] * invN - m0 * m0;
  float a0 = g0[c] * rsqrtf(v0 + 1e-5f);
  float h0 = b0[c] - m0 * a0;
  float m1 = sums1[c] * invN;
  float v1 = sums1[256 + c] * invN - m1 * m1;
  float a1 = g1[c] * rsqrtf(v1 + 1e-5f);
  float h1 = b1[c] - m1 * a1;
  float4 t = *reinterpret_cast<const float4*>(T + i4);
  float4 s = *reinterpret_cast<const float4*>(S + i4);
  float4 o;
  o.x = fmaxf(fmaf(t.x, a0, h0) + fmaf(s.x, a1, h1), 0.f);
  o.y = fmaxf(fmaf(t.y, a0, h0) + fmaf(s.y, a1, h1), 0.f);
  o.z = fmaxf(fmaf(t.z, a0, h0) + fmaf(s.z, a1, h1), 0.f);
  o.w = fmaxf(fmaf(t.w, a0, h0) + fmaf(s.w, a1, h1), 0.f);
  *reinterpret_cast<float4*>(O + i4) = o;
}

// ---------------- final: out = bn(F) as f32 ---------------------------------
__global__ __launch_bounds__(256)
void writeout_kernel(const float* __restrict__ F, const float* __restrict__ sums,
                     const float* __restrict__ gam, const float* __restrict__ bet,
                     float* __restrict__ out) {
  const int i4 = (blockIdx.x * 256 + threadIdx.x) << 2;
  const int c = (i4 >> 10) & 63;
  const float invN = 1.f / 16384.f;
  float m  = sums[c] * invN;
  float vv = sums[256 + c] * invN - m * m;
  float sc = gam[c] * rsqrtf(vv + 1e-5f);
  float sh = bet[c] - m * sc;
  float4 v = *reinterpret_cast<const float4*>(F + i4);
  float4 o;
  o.x = fmaf(v.x, sc, sh); o.y = fmaf(v.y, sc, sh);
  o.z = fmaf(v.z, sc, sh); o.w = fmaf(v.w, sc, sh);
  *reinterpret_cast<float4*>(out + i4) = o;
}

// ============================ host side =====================================
extern "C" void kernel_launch(void* const* d_in, const int* in_sizes, int n_in,
                              void* d_out, int out_size, void* d_ws, size_t ws_size,
                              hipStream_t stream) {
  float* wsf = (float*)d_ws;
  const size_t M1 = (size_t)1 << 20;
  const size_t H1 = (size_t)1 << 19;

  float* R0  = wsf;                // 4M (first 2M: bf16 Q/K buffers)
  float* R1  = wsf + 4 * M1;       // 4M
  float* XBA = wsf + 8 * M1;       // 1M
  float* XAA = wsf + 9 * M1;       // 1M
  float* R2  = wsf + 10 * M1;      // 4M (PART, then SC)
  float* O1  = wsf + 14 * M1;      // 2M
  float* tail = wsf + 16 * M1;
  float* bsum  = tail;             // 16
  float* stats = tail + 16;        // 12 * 512

  unsigned short* QAt = (unsigned short*)R0;              // [b][n][c] bf16
  unsigned short* QBt = (unsigned short*)(R0 + H1);
  unsigned short* KAc = (unsigned short*)(R0 + 2 * H1);   // [b][c][n] bf16
  unsigned short* KBc = (unsigned short*)(R0 + 3 * H1);

  // all inputs consumed directly as f32
  const float* pp[46];
  for (int i = 0; i < 46 && i < n_in; ++i) pp[i] = (const float*)d_in[i];
  const float* XAF = pp[0];
  const float* XBF = pp[1];

  init_kernel<<<1, 256, 0, stream>>>(tail, 16 + 12 * 512);

  float* ST[12];
  for (int i = 0; i < 12; ++i) ST[i] = stats + i * 512;

  // ---- q/k convs -> bf16 dual layouts ----
  dim3 gq(16, 2, BATCH);
  conv_qk_kernel<0><<<gq, 256, 0, stream>>>(XAF, pp[2], pp[3], QAt);
  conv_qk_kernel<0><<<gq, 256, 0, stream>>>(XBF, pp[4], pp[5], QBt);
  conv_qk_kernel<1><<<gq, 256, 0, stream>>>(XAF, pp[6], pp[7], KAc);
  conv_qk_kernel<1><<<gq, 256, 0, stream>>>(XBF, pp[8], pp[9], KBc);

  // ---- MFMA attention (4-way split partials in R2) ----
  pv_mfma_kernel<<<dim3(16, 4, BATCH), 256, 0, stream>>>(QAt, QBt, KBc, R2, bsum);
  part_reduce_kernel<<<1024, 256, 0, stream>>>(R2, XBA);
  tpv_mfma_kernel<<<dim3(16, 4, BATCH), 256, 0, stream>>>(QAt, QBt, KAc, R2);
  part_reduce_kernel<<<1024, 256, 0, stream>>>(R2, XAA);

  for (int sbi = 0; sbi < 2; ++sbi) {
    const float* XR  = sbi ? XBF : XAF;
    const float* ATT = sbi ? XAA : XBA;
    const int base1 = sbi ? 16 : 10;
    const int base2 = sbi ? 31 : 22;
    const int baseo = sbi ? 43 : 40;
    float* s_t1a = ST[sbi * 6 + 0];
    float* s_t2a = ST[sbi * 6 + 1];
    float* s_t1b = ST[sbi * 6 + 2];
    float* s_t2b = ST[sbi * 6 + 3];
    float* s_sc  = ST[sbi * 6 + 4];
    float* s_o   = ST[sbi * 6 + 5];

    // ---- block 1 (128 -> 128) ----
    convg_kernel<128, 8, 3, true><<<dim3(16, 2, BATCH), 256, 0, stream>>>(
        XR, ATT, pp[base1 + 0], nullptr, nullptr, nullptr, nullptr, bsum, R0, s_t1a, 128);
    convg_kernel<128, 8, 2, true><<<dim3(16, 2, BATCH), 256, 0, stream>>>(
        R0, nullptr, pp[base1 + 3], nullptr, s_t1a, pp[base1 + 1], pp[base1 + 2], nullptr,
        R1, s_t2a, 128);
    epil_add_kernel<<<BATCH * 128, 256, 0, stream>>>(
        R1, s_t2a, pp[base1 + 4], pp[base1 + 5], XR, ATT, bsum, O1);

    // ---- block 2 (128 -> 256, with shortcut) ----
    convg_kernel<128, 8, 0, true><<<dim3(32, 2, BATCH), 256, 0, stream>>>(
        O1, nullptr, pp[base2 + 0], nullptr, nullptr, nullptr, nullptr, nullptr,
        R0, s_t1b, 256);
    convg_kernel<256, 8, 2, true><<<dim3(32, 2, BATCH), 256, 0, stream>>>(
        R0, nullptr, pp[base2 + 3], nullptr, s_t1b, pp[base2 + 1], pp[base2 + 2], nullptr,
        R1, s_t2b, 256);
    convg_kernel<128, 8, 0, true><<<dim3(32, 2, BATCH), 256, 0, stream>>>(
        O1, nullptr, pp[base2 + 6], nullptr, nullptr, nullptr, nullptr, nullptr,
        R2, s_sc, 256);
    epil2_kernel<<<BATCH * 256, 256, 0, stream>>>(
        R1, s_t2b, pp[base2 + 4], pp[base2 + 5], R2, s_sc, pp[base2 + 7], pp[base2 + 8], R0);

    // ---- output conv (256 -> 64) + BN ----
    convg_kernel<256, 4, 0, true><<<dim3(16, 2, BATCH), 256, 0, stream>>>(
        R0, nullptr, pp[baseo + 0], nullptr, nullptr, nullptr, nullptr, nullptr,
        R1, s_o, 64);
    writeout_kernel<<<1024, 256, 0, stream>>>(
        R1, s_o, pp[baseo + 1], pp[baseo + 2], (float*)d_out + sbi * M1);
  }
}